// Round 3
// baseline (448.186 us; speedup 1.0000x reference)
//
#include <hip/hip_runtime.h>

typedef __attribute__((ext_vector_type(8))) short bf16x8;
typedef __attribute__((ext_vector_type(4))) float f32x4;

#define D_MODEL 1024
#define T_LEN 2048
#define BATCH 2
#define N_HEADS 16
#define D_HEAD 64
#define WINDOW 256
#define N_STATE 128
#define D_FF 4096
#define N_CAT 4224   // 4*D_MODEL + N_STATE
#define LDQ 4352     // N_CAT padded to 17*256 for the 256-tile GEMM
#define M_ROWS 4096  // B*T

static __device__ __forceinline__ float bf2f(unsigned short u) {
  union { unsigned int i; float f; } v; v.i = ((unsigned int)u) << 16; return v.f;
}
static __device__ __forceinline__ unsigned short f2bf(float f) {
  unsigned int x = __float_as_uint(f);
  return (unsigned short)((x + 0x7FFFu + ((x >> 16) & 1u)) >> 16);
}

static __device__ __forceinline__ void gl_lds16(const void* g, void* l) {
  __builtin_amdgcn_global_load_lds(
      (const __attribute__((address_space(1))) unsigned int*)g,
      (__attribute__((address_space(3))) unsigned int*)l, 16, 0, 0);
}

// ---------------------------------------------------------------------------
// Transpose + f32->bf16 convert: dst[(n_off+n)*ldd + k] = bf16(src[k*N + n])
// ---------------------------------------------------------------------------
__global__ __launch_bounds__(256) void transpose_cvt(
    const float* __restrict__ src, unsigned short* __restrict__ dst,
    int K, int N, int n_off, int ldd)
{
  __shared__ float tile[32][33];
  const int kt = blockIdx.x * 32, nt = blockIdx.y * 32;
  const int c = threadIdx.x & 31, r0 = threadIdx.x >> 5;
#pragma unroll
  for (int i = 0; i < 4; i++) {
    const int r = r0 + i * 8;
    tile[r][c] = src[(size_t)(kt + r) * N + nt + c];
  }
  __syncthreads();
#pragma unroll
  for (int i = 0; i < 4; i++) {
    const int r = r0 + i * 8;
    dst[(size_t)(n_off + nt + r) * ldd + kt + c] = f2bf(tile[c][r]);
  }
}

__global__ __launch_bounds__(256) void build_bcat(
    const float* __restrict__ bq, const float* __restrict__ bk,
    const float* __restrict__ bv, const float* __restrict__ bg,
    float* __restrict__ bcat)
{
  const int i = blockIdx.x * 256 + threadIdx.x;
  if (i < LDQ) {
    float v = 0.0f;
    if (i < 1024)      v = bq[i];
    else if (i < 2048) v = bk[i - 1024];
    else if (i < 3072) v = bv[i - 2048];
    else if (i < 4096) v = bg[i - 3072];
    bcat[i] = v;   // 4096..4351 -> 0 (Bw has no bias; pad cols)
  }
}

// ---------------------------------------------------------------------------
// LayerNorm: one block per row (1024 cols), bf16 output
// ---------------------------------------------------------------------------
__global__ __launch_bounds__(256) void ln_kernel(
    const float* __restrict__ x, const float* __restrict__ g,
    const float* __restrict__ b, unsigned short* __restrict__ out)
{
  const int row = blockIdx.x, tid = threadIdx.x;
  const float4 xv = ((const float4*)(x + (size_t)row * 1024))[tid];
  float s  = xv.x + xv.y + xv.z + xv.w;
  float s2 = xv.x * xv.x + xv.y * xv.y + xv.z * xv.z + xv.w * xv.w;
#pragma unroll
  for (int off = 32; off >= 1; off >>= 1) {
    s  += __shfl_down(s, off);
    s2 += __shfl_down(s2, off);
  }
  __shared__ float red[8];
  const int wave = tid >> 6;
  if ((tid & 63) == 0) { red[wave] = s; red[4 + wave] = s2; }
  __syncthreads();
  s  = red[0] + red[1] + red[2] + red[3];
  s2 = red[4] + red[5] + red[6] + red[7];
  const float mu = s * (1.0f / 1024.0f);
  const float rs = rsqrtf(s2 * (1.0f / 1024.0f) - mu * mu + 1e-5f);
  const float4 gv = ((const float4*)g)[tid];
  const float4 bv = ((const float4*)b)[tid];
  ushort4 o;
  o.x = f2bf((xv.x - mu) * rs * gv.x + bv.x);
  o.y = f2bf((xv.y - mu) * rs * gv.y + bv.y);
  o.z = f2bf((xv.z - mu) * rs * gv.z + bv.z);
  o.w = f2bf((xv.w - mu) * rs * gv.w + bv.w);
  ((ushort4*)(out + (size_t)row * 1024))[tid] = o;
}

// ---------------------------------------------------------------------------
// 256x256 tile GEMM, BK=64, 8 waves, double-buffered 128KB LDS,
// counted-vmcnt 4-phase pipeline (T3+T4), both-sides XOR swizzle (T2),
// setprio around MFMA clusters (T5), bijective XCD swizzle (T1).
// C[M,N] = A[M,K] @ BT[N,K]^T + bias, ACT: 0=none 2=gelu. bf16 out.
// ---------------------------------------------------------------------------
__device__ __forceinline__ void lda_frags(const unsigned short* buf, int base_row,
                                          int l15, int lg, bf16x8 af[4][2]) {
#pragma unroll
  for (int mf4 = 0; mf4 < 4; mf4++)
#pragma unroll
    for (int ks = 0; ks < 2; ks++) {
      const int R = base_row + mf4 * 16 + l15;
      const int off = (R << 7) + ((ks * 64 + lg * 16) ^ ((R & 7) << 4));
      af[mf4][ks] = *(const bf16x8*)((const char*)buf + off);
    }
}
__device__ __forceinline__ void ldb_frags(const unsigned short* buf, int base_row,
                                          int l15, int lg, bf16x8 bf[2][2]) {
#pragma unroll
  for (int nf2 = 0; nf2 < 2; nf2++)
#pragma unroll
    for (int ks = 0; ks < 2; ks++) {
      const int R = base_row + nf2 * 16 + l15;
      const int off = (R << 7) + ((ks * 64 + lg * 16) ^ ((R & 7) << 4));
      bf[nf2][ks] = *(const bf16x8*)((const char*)buf + off);
    }
}
__device__ __forceinline__ void mm16(f32x4 acc[8][4], int mh, int nh,
                                     const bf16x8 af[4][2], const bf16x8 bf[2][2]) {
  __builtin_amdgcn_s_setprio(1);
#pragma unroll
  for (int mf4 = 0; mf4 < 4; mf4++)
#pragma unroll
    for (int nf2 = 0; nf2 < 2; nf2++)
#pragma unroll
      for (int ks = 0; ks < 2; ks++)
        acc[mh * 4 + mf4][nh * 2 + nf2] = __builtin_amdgcn_mfma_f32_16x16x32_bf16(
            af[mf4][ks], bf[nf2][ks], acc[mh * 4 + mf4][nh * 2 + nf2], 0, 0, 0);
  __builtin_amdgcn_s_setprio(0);
}

template<int ACT>
__global__ __launch_bounds__(512, 2) void gemm256(
    const unsigned short* __restrict__ A, const unsigned short* __restrict__ BT,
    const float* __restrict__ bias, unsigned short* __restrict__ C,
    int M, int N, int K, int nbx)
{
  extern __shared__ char smem[];
  unsigned short* A0 = (unsigned short*)smem;          // 32KB each
  unsigned short* B0 = A0 + 16384;
  unsigned short* A1 = B0 + 16384;
  unsigned short* B1 = A1 + 16384;

  const int nwg = gridDim.x;
  int bid = blockIdx.x;
  { // bijective XCD swizzle (m204)
    const int q = nwg >> 3, r = nwg & 7, x = bid & 7, o = bid >> 3;
    bid = (x < r ? x * (q + 1) : r * (q + 1) + (x - r) * q) + o;
  }
  const int m0 = (bid % nbx) * 256;
  const int n0 = (bid / nbx) * 256;

  const int tid = threadIdx.x, lane = tid & 63, wave = tid >> 6;
  const int wmi = wave >> 2, wni = wave & 3;
  const int l15 = lane & 15, lg = lane >> 4;
  const int NT = K >> 6;

  f32x4 acc[8][4];
#pragma unroll
  for (int i = 0; i < 8; i++)
#pragma unroll
    for (int j = 0; j < 4; j++) acc[i][j] = (f32x4){0.f, 0.f, 0.f, 0.f};

  // staging source pointers: physical LDS byte p = hj*8192 + tid*16,
  // logical (R, cb): R = p>>7, cb = (p&127) ^ ((R&7)<<4)  (involution)
  const char* srcA[4]; const char* srcB[4];
#pragma unroll
  for (int hj = 0; hj < 4; hj++) {
    const int p = hj * 8192 + tid * 16;
    const int R = p >> 7;
    const int cb = (p & 127) ^ ((R & 7) << 4);
    srcA[hj] = (const char*)A + (size_t)(m0 + R) * (size_t)(K * 2) + cb;
    srcB[hj] = (const char*)BT + (size_t)(n0 + R) * (size_t)(K * 2) + cb;
  }

#define STAGE_(arr, kt, h, buf) do {                                                     \
    gl_lds16(arr[2*(h)]   + (size_t)(kt)*128, (char*)(buf) + (2*(h))*8192   + tid*16);   \
    gl_lds16(arr[2*(h)+1] + (size_t)(kt)*128, (char*)(buf) + (2*(h)+1)*8192 + tid*16);   \
  } while (0)

  // prologue: B0, A0 -> buf0 ; B1 -> buf1 ; tile0 resident, B1 may fly
  STAGE_(srcB, 0, 0, B0); STAGE_(srcB, 0, 1, B0);
  STAGE_(srcA, 0, 0, A0); STAGE_(srcA, 0, 1, A0);
  STAGE_(srcB, 1, 0, B1); STAGE_(srcB, 1, 1, B1);
  asm volatile("s_waitcnt vmcnt(4)" ::: "memory");
  __builtin_amdgcn_s_barrier();

  bf16x8 af[4][2], bf0[2][2], bf1[2][2];
  const int arow = wmi * 128, brow = wni * 64;

#define GROUP(t, Ac, Bc, Ao, Bo) do {                                         \
    /* ph1: Q(0,0) */                                                         \
    lda_frags(Ac, arow, l15, lg, af);                                         \
    ldb_frags(Bc, brow, l15, lg, bf0);                                        \
    if ((t) + 1 < NT) STAGE_(srcA, (t) + 1, 0, Ao);                           \
    mm16(acc, 0, 0, af, bf0);                                                 \
    __builtin_amdgcn_s_barrier();                                             \
    /* ph2: Q(0,1) */                                                         \
    ldb_frags(Bc, brow + 32, l15, lg, bf1);                                   \
    if ((t) + 1 < NT) STAGE_(srcA, (t) + 1, 1, Ao);                           \
    mm16(acc, 0, 1, af, bf1);                                                 \
    __builtin_amdgcn_s_barrier();                                             \
    /* ph3: Q(1,0) — B-region of Bc fully read by ph2 barrier */              \
    lda_frags(Ac, arow + 64, l15, lg, af);                                    \
    if ((t) + 2 < NT) STAGE_(srcB, (t) + 2, 0, Bc);                           \
    mm16(acc, 1, 0, af, bf0);                                                 \
    __builtin_amdgcn_s_barrier();                                             \
    /* ph4: Q(1,1) + tile checkpoint */                                       \
    if ((t) + 2 < NT) {                                                       \
      STAGE_(srcB, (t) + 2, 1, Bc);                                           \
      mm16(acc, 1, 1, af, bf1);                                               \
      asm volatile("s_waitcnt vmcnt(4)" ::: "memory");                        \
    } else {                                                                  \
      mm16(acc, 1, 1, af, bf1);                                               \
      asm volatile("s_waitcnt vmcnt(0)" ::: "memory");                        \
    }                                                                         \
    __builtin_amdgcn_s_barrier();                                             \
  } while (0)

  for (int t = 0; t < NT; t += 2) {
    GROUP(t, A0, B0, A1, B1);
    GROUP(t + 1, A1, B1, A0, B0);
  }
#undef GROUP
#undef STAGE_

  // epilogue
  const int crow0 = m0 + wmi * 128 + lg * 4;
  const int ccol0 = n0 + wni * 64 + l15;
#pragma unroll
  for (int mf = 0; mf < 8; mf++)
#pragma unroll
    for (int r = 0; r < 4; r++) {
      const size_t rb = (size_t)(crow0 + mf * 16 + r) * N;
#pragma unroll
      for (int nf = 0; nf < 4; nf++) {
        const int col = ccol0 + nf * 16;
        float v = acc[mf][nf][r] + bias[col];
        if (ACT == 2) v = 0.5f * v * (1.0f + erff(v * 0.70710678118654752f));
        C[rb + col] = f2bf(v);
      }
    }
}

// ---------------------------------------------------------------------------
// Fallback / small GEMM: 128xBN tile, BK=32, global_load_lds, 2-phase
// ---------------------------------------------------------------------------
template<int BN, int ACT, bool OUT_BF16, bool RESID>
__global__ __launch_bounds__(256) void gemm_bt(
    const unsigned short* __restrict__ A, const unsigned short* __restrict__ BT,
    const float* __restrict__ bias, const float* __restrict__ resid,
    void* __restrict__ Cout, int M, int N, int K)
{
  constexpr int NI = BN / 32;
  __shared__ unsigned short As[128][32];
  __shared__ unsigned short Bs[BN][32];
  const int m0 = blockIdx.x * 128, n0 = blockIdx.y * BN;
  const int tid = threadIdx.x, lane = tid & 63, wave = tid >> 6;
  const int l15 = lane & 15, lg = lane >> 4;
  int wm, wn;
  if (BN == 128) { wm = (wave >> 1) * 64; wn = (wave & 1) * 64; }
  else           { wm = (wave & 1) * 64;  wn = (wave >> 1) * 32; }
  f32x4 acc[4][NI];
#pragma unroll
  for (int i = 0; i < 4; i++)
#pragma unroll
    for (int j = 0; j < NI; j++) acc[i][j] = (f32x4){0.f, 0.f, 0.f, 0.f};

  const int srow = lane >> 2;
  const int scol = (lane & 3) * 8;
  const unsigned short* Ag = A + (size_t)(m0 + wave * 32 + srow) * K + scol;
  unsigned short* Al = &As[wave * 32 + srow][scol];
  const unsigned short* Bg;
  unsigned short* Bl;
  if (BN == 128) { Bg = BT + (size_t)(n0 + wave * 32 + srow) * K + scol; Bl = &Bs[wave * 32 + srow][0] + scol; }
  else           { Bg = BT + (size_t)(n0 + wave * 16 + srow) * K + scol; Bl = &Bs[wave * 16 + srow][0] + scol; }
  const size_t kstride16 = (size_t)16 * K;

  for (int k0 = 0; k0 < K; k0 += 32) {
    __syncthreads();
    gl_lds16(Ag + k0, Al);
    gl_lds16(Ag + k0 + kstride16, Al + 16 * 32);
    gl_lds16(Bg + k0, Bl);
    if (BN == 128) gl_lds16(Bg + k0 + kstride16, Bl + 16 * 32);
    __syncthreads();
    bf16x8 af[4], bfr[NI];
#pragma unroll
    for (int mi = 0; mi < 4; mi++)
      af[mi] = *(const bf16x8*)&As[wm + mi * 16 + l15][lg * 8];
#pragma unroll
    for (int ni = 0; ni < NI; ni++)
      bfr[ni] = *(const bf16x8*)&Bs[wn + ni * 16 + l15][lg * 8];
#pragma unroll
    for (int mi = 0; mi < 4; mi++)
#pragma unroll
      for (int ni = 0; ni < NI; ni++)
        acc[mi][ni] = __builtin_amdgcn_mfma_f32_16x16x32_bf16(af[mi], bfr[ni], acc[mi][ni], 0, 0, 0);
  }

#pragma unroll
  for (int ni = 0; ni < NI; ni++) {
    const int col = n0 + wn + ni * 16 + l15;
    const float bv = bias ? bias[col] : 0.0f;
#pragma unroll
    for (int mi = 0; mi < 4; mi++) {
      const int rbase = m0 + wm + mi * 16 + lg * 4;
#pragma unroll
      for (int r = 0; r < 4; r++) {
        float v = acc[mi][ni][r] + bv;
        if (ACT == 2) v = 0.5f * v * (1.0f + erff(v * 0.70710678118654752f));
        const size_t idx = (size_t)(rbase + r) * N + col;
        if (RESID) v += resid[idx];
        if (OUT_BF16) ((unsigned short*)Cout)[idx] = f2bf(v);
        else          ((float*)Cout)[idx] = v;
      }
    }
  }
}

// ---------------------------------------------------------------------------
// Windowed causal attention, all-MFMA (unchanged, LDQ stride)
// ---------------------------------------------------------------------------
__global__ __launch_bounds__(256) void attn_kernel(
    const unsigned short* __restrict__ qkvgu, unsigned short* __restrict__ ao)
{
  __shared__ float S[16][276];
  __shared__ unsigned short Vt[288][68];
  unsigned short* P = (unsigned short*)&S[0][0];

  const int bx = ((blockIdx.x & 7) << 4) | (blockIdx.x >> 3);
  const int q0 = bx * 16;
  const int h  = blockIdx.y;
  const int b  = blockIdx.z;
  const int tid = threadIdx.x, lane = tid & 63, wave = tid >> 6;
  const int l15 = lane & 15, lg = lane >> 4;
  const size_t rowbase = (size_t)b * T_LEN;

  {
    const int cg = (tid & 3) * 16;
    const int rr = tid >> 2;
#pragma unroll
    for (int j = 0; j < 5; j++) {
      const int row = j * 64 + rr;
      if (row < 288) {
        const int vrow = q0 - 256 + row;
        uint4 d0 = {0u, 0u, 0u, 0u}, d1 = {0u, 0u, 0u, 0u};
        if (vrow >= 0 && row < 272) {
          const unsigned short* vp = qkvgu + (rowbase + vrow) * LDQ + 2048 + h * 64 + cg;
          d0 = *(const uint4*)vp;
          d1 = *(const uint4*)(vp + 8);
        }
        unsigned short* wp = &Vt[row][cg];
        ((uint2*)wp)[0] = make_uint2(d0.x, d0.y);
        ((uint2*)wp)[1] = make_uint2(d0.z, d0.w);
        ((uint2*)wp)[2] = make_uint2(d1.x, d1.y);
        ((uint2*)wp)[3] = make_uint2(d1.z, d1.w);
      }
    }
  }

  {
    const unsigned short* qp = qkvgu + (rowbase + q0 + l15) * LDQ + h * 64 + lg * 8;
    const bf16x8 aq0 = *(const bf16x8*)qp;
    const bf16x8 aq1 = *(const bf16x8*)(qp + 32);
    for (int kt = wave; kt < 17; kt += 4) {
      const int kbase = q0 - 256 + kt * 16;
      const int krow = kbase + l15;
      const int krc = krow < 0 ? 0 : krow;
      const unsigned short* kp = qkvgu + (rowbase + krc) * LDQ + 1024 + h * 64 + lg * 8;
      const bf16x8 bk0 = *(const bf16x8*)kp;
      const bf16x8 bk1 = *(const bf16x8*)(kp + 32);
      f32x4 sacc = (f32x4){0.f, 0.f, 0.f, 0.f};
      sacc = __builtin_amdgcn_mfma_f32_16x16x32_bf16(aq0, bk0, sacc, 0, 0, 0);
      sacc = __builtin_amdgcn_mfma_f32_16x16x32_bf16(aq1, bk1, sacc, 0, 0, 0);
#pragma unroll
      for (int r = 0; r < 4; r++) {
        const int qi = q0 + lg * 4 + r;
        const int kj = kbase + l15;
        const bool ok = (kj >= 0) && (kj <= qi) && (qi - kj < WINDOW);
        S[lg * 4 + r][kt * 16 + l15] = ok ? sacc[r] * 0.125f : -1e30f;
      }
    }
  }
  __syncthreads();

  {
    const int q = tid >> 4, sub = tid & 15;
    float mx = -1e30f;
    for (int c = sub; c < 272; c += 16) mx = fmaxf(mx, S[q][c]);
#pragma unroll
    for (int off = 8; off >= 1; off >>= 1) mx = fmaxf(mx, __shfl_xor(mx, off));
    float sum = 0.f;
    for (int c = sub; c < 272; c += 16) sum += __expf(S[q][c] - mx);
#pragma unroll
    for (int off = 8; off >= 1; off >>= 1) sum += __shfl_xor(sum, off);
    const float inv = 1.0f / sum;
    unsigned short* Prow = P + q * 552;
    for (int c = sub; c < 288; c += 16) {
      const float pv = (c < 272) ? __expf(S[q][c] - mx) * inv : 0.0f;
      Prow[c] = f2bf(pv);
    }
  }
  __syncthreads();

  {
    f32x4 oacc = (f32x4){0.f, 0.f, 0.f, 0.f};
    const int dn = wave * 16 + l15;
#pragma unroll
    for (int ks = 0; ks < 9; ks++) {
      const bf16x8 pa = *(const bf16x8*)(P + l15 * 552 + ks * 32 + lg * 8);
      bf16x8 vb;
      const int kb = ks * 32 + lg * 8;
#pragma unroll
      for (int j = 0; j < 8; j++) ((unsigned short*)&vb)[j] = Vt[kb + j][dn];
      oacc = __builtin_amdgcn_mfma_f32_16x16x32_bf16(pa, vb, oacc, 0, 0, 0);
    }
#pragma unroll
    for (int r = 0; r < 4; r++)
      ao[(rowbase + q0 + lg * 4 + r) * D_MODEL + h * 64 + dn] = f2bf(oacc[r]);
  }
}

// ---------------------------------------------------------------------------
// Chunked SSM scan (|A|<0.1 => A^512 underflows; carry fixup self-terminates)
// ---------------------------------------------------------------------------
__global__ __launch_bounds__(1024) void scan_kernel(
    const unsigned short* __restrict__ qkvgu, const float* __restrict__ Avec,
    const float* __restrict__ s0, unsigned short* __restrict__ states,
    float* __restrict__ out_state)
{
  __shared__ float finals[4][256];
  const int tid = threadIdx.x;
  const int bn = tid & 255;
  const int b = bn >> 7, n = bn & 127;
  const int c = tid >> 8;
  const float a = Avec[n];
  float s = (c == 0) ? s0[bn] : 0.0f;
  const size_t ubase = (size_t)b * T_LEN * LDQ + 4096 + n;
  unsigned short* sp = states + (size_t)b * T_LEN * N_STATE + n;
  const int t0 = c * 512;
#pragma unroll 8
  for (int t = t0; t < t0 + 512; t++) {
    s = fmaf(a, s, bf2f(qkvgu[ubase + (size_t)t * LDQ]));
    sp[(size_t)t * N_STATE] = f2bf(s);
  }
  finals[c][bn] = s;
  if (c == 3) out_state[bn] = s;
  __syncthreads();
  if (c > 0) {
    const float carry = finals[c - 1][bn];
    float f = a;
    for (int t = t0; t < t0 + 512; t++) {
      if (f == 0.0f) break;
      const float v = bf2f(sp[(size_t)t * N_STATE]) + f * carry;
      sp[(size_t)t * N_STATE] = f2bf(v);
      f *= a;
    }
  }
}

// ---------------------------------------------------------------------------
// Gated fusion: out = x + g*attn + (1-g)*ssm,  g = sigmoid(xg)
// ---------------------------------------------------------------------------
__global__ __launch_bounds__(256) void fusion_kernel(
    const float* __restrict__ x, const unsigned short* __restrict__ qkvgu,
    const unsigned short* __restrict__ attn, const unsigned short* __restrict__ ssm,
    float* __restrict__ out)
{
  const int i = blockIdx.x * 256 + threadIdx.x;
  const size_t e4 = (size_t)i * 4;
  const int row = i >> 8;
  const int col = (i & 255) * 4;
  const float4 xv = *(const float4*)(x + e4);
  const ushort4 au = *(const ushort4*)(attn + e4);
  const ushort4 su = *(const ushort4*)(ssm + e4);
  const ushort4 gu = *(const ushort4*)(qkvgu + (size_t)row * LDQ + 3072 + col);
  float4 o;
  const float g0 = 1.0f / (1.0f + __expf(-bf2f(gu.x)));
  const float g1 = 1.0f / (1.0f + __expf(-bf2f(gu.y)));
  const float g2 = 1.0f / (1.0f + __expf(-bf2f(gu.z)));
  const float g3 = 1.0f / (1.0f + __expf(-bf2f(gu.w)));
  o.x = xv.x + g0 * bf2f(au.x) + (1.0f - g0) * bf2f(su.x);
  o.y = xv.y + g1 * bf2f(au.y) + (1.0f - g1) * bf2f(su.y);
  o.z = xv.z + g2 * bf2f(au.z) + (1.0f - g2) * bf2f(su.z);
  o.w = xv.w + g3 * bf2f(au.w) + (1.0f - g3) * bf2f(su.w);
  *(float4*)(out + e4) = o;
}

// ---------------------------------------------------------------------------
extern "C" void kernel_launch(void* const* d_in, const int* in_sizes, int n_in,
                              void* d_out, int out_size, void* d_ws, size_t ws_size,
                              hipStream_t stream)
{
  const float* x     = (const float*)d_in[0];
  const float* ssm0  = (const float*)d_in[1];
  const float* ln1_g = (const float*)d_in[2];
  const float* ln1_b = (const float*)d_in[3];
  const float* wq    = (const float*)d_in[4];
  const float* bq    = (const float*)d_in[5];
  const float* wk    = (const float*)d_in[6];
  const float* bk    = (const float*)d_in[7];
  const float* wv    = (const float*)d_in[8];
  const float* bv    = (const float*)d_in[9];
  const float* wo    = (const float*)d_in[10];
  const float* bo    = (const float*)d_in[11];
  const float* wg    = (const float*)d_in[12];
  const float* bg    = (const float*)d_in[13];
  const float* Av    = (const float*)d_in[14];
  const float* Bw    = (const float*)d_in[15];
  const float* Cw    = (const float*)d_in[16];
  const float* ln2_g = (const float*)d_in[17];
  const float* ln2_b = (const float*)d_in[18];
  const float* w1    = (const float*)d_in[19];
  const float* b1    = (const float*)d_in[20];
  const float* w2    = (const float*)d_in[21];
  const float* b2    = (const float*)d_in[22];

  char* p = (char*)d_ws;
  auto take = [&](size_t bytes) { char* q = p; p += (bytes + 255) & ~(size_t)255; return q; };
  unsigned short* WcatT  = (unsigned short*)take((size_t)LDQ * 1024 * 2);
  unsigned short* woT    = (unsigned short*)take((size_t)1024 * 1024 * 2);
  unsigned short* CwT    = (unsigned short*)take((size_t)1024 * 128 * 2);
  unsigned short* w1T    = (unsigned short*)take((size_t)4096 * 1024 * 2);
  unsigned short* w2T    = (unsigned short*)take((size_t)1024 * 4096 * 2);
  float*          bcat   = (float*)take((size_t)LDQ * 4);
  unsigned short* xn     = (unsigned short*)take((size_t)M_ROWS * 1024 * 2);
  unsigned short* qkvgu  = (unsigned short*)take((size_t)M_ROWS * LDQ * 2);
  unsigned short* ao     = (unsigned short*)take((size_t)M_ROWS * 1024 * 2);
  unsigned short* states = (unsigned short*)take((size_t)M_ROWS * N_STATE * 2);
  unsigned short* attn_o = (unsigned short*)take((size_t)M_ROWS * 1024 * 2);
  unsigned short* ssm_o  = (unsigned short*)take((size_t)M_ROWS * 1024 * 2);
  unsigned short* hbuf   = qkvgu;   // alias: qkvgu dead after fusion

  float* outx = (float*)d_out;
  float* out_state = outx + (size_t)M_ROWS * 1024;

  // 128KB dynamic LDS opt-in; fall back to 2-phase path if not available
  const bool big_ok =
      hipFuncSetAttribute((const void*)gemm256<0>,
                          hipFuncAttributeMaxDynamicSharedMemorySize, 131072) == hipSuccess &&
      hipFuncSetAttribute((const void*)gemm256<2>,
                          hipFuncAttributeMaxDynamicSharedMemorySize, 131072) == hipSuccess;

  // --- weight prep (bf16, transposed) ---
  transpose_cvt<<<dim3(32, 32), 256, 0, stream>>>(wq, WcatT, 1024, 1024, 0, 1024);
  transpose_cvt<<<dim3(32, 32), 256, 0, stream>>>(wk, WcatT, 1024, 1024, 1024, 1024);
  transpose_cvt<<<dim3(32, 32), 256, 0, stream>>>(wv, WcatT, 1024, 1024, 2048, 1024);
  transpose_cvt<<<dim3(32, 32), 256, 0, stream>>>(wg, WcatT, 1024, 1024, 3072, 1024);
  transpose_cvt<<<dim3(32, 4), 256, 0, stream>>>(Bw, WcatT, 1024, 128, 4096, 1024);
  transpose_cvt<<<dim3(32, 32), 256, 0, stream>>>(wo, woT, 1024, 1024, 0, 1024);
  transpose_cvt<<<dim3(4, 32), 256, 0, stream>>>(Cw, CwT, 128, 1024, 0, 128);
  transpose_cvt<<<dim3(32, 128), 256, 0, stream>>>(w1, w1T, 1024, 4096, 0, 1024);
  transpose_cvt<<<dim3(128, 32), 256, 0, stream>>>(w2, w2T, 4096, 1024, 0, 4096);
  build_bcat<<<17, 256, 0, stream>>>(bq, bk, bv, bg, bcat);

  // --- forward ---
  ln_kernel<<<M_ROWS, 256, 0, stream>>>(x, ln1_g, ln1_b, xn);
  if (big_ok)
    gemm256<0><<<272, 512, 131072, stream>>>(xn, WcatT, bcat, qkvgu, M_ROWS, LDQ, 1024, 16);
  else
    gemm_bt<128, 0, true, false><<<dim3(32, 34), 256, 0, stream>>>(
        xn, WcatT, bcat, nullptr, qkvgu, M_ROWS, LDQ, 1024);
  attn_kernel<<<dim3(128, 16, 2), 256, 0, stream>>>(qkvgu, ao);
  scan_kernel<<<1, 1024, 0, stream>>>(qkvgu, Av, ssm0, states, out_state);
  gemm_bt<64, 0, true, false><<<dim3(32, 16), 256, 0, stream>>>(
      ao, woT, bo, nullptr, attn_o, M_ROWS, 1024, 1024);
  gemm_bt<64, 0, true, false><<<dim3(32, 16), 256, 0, stream>>>(
      states, CwT, nullptr, nullptr, ssm_o, M_ROWS, 1024, 128);
  fusion_kernel<<<4096, 256, 0, stream>>>(x, qkvgu, attn_o, ssm_o, outx);
  ln_kernel<<<M_ROWS, 256, 0, stream>>>(outx, ln2_g, ln2_b, xn);
  if (big_ok)
    gemm256<2><<<256, 512, 131072, stream>>>(xn, w1T, b1, hbuf, M_ROWS, D_FF, 1024, 16);
  else
    gemm_bt<128, 2, true, false><<<dim3(32, 32), 256, 0, stream>>>(
        xn, w1T, b1, nullptr, hbuf, M_ROWS, D_FF, 1024);
  gemm_bt<64, 0, false, true><<<dim3(32, 16), 256, 0, stream>>>(
      hbuf, w2T, b2, outx, outx, M_ROWS, 1024, D_FF);
}

// Round 4
// 410.304 us; speedup vs baseline: 1.0923x; 1.0923x over previous
//
#include <hip/hip_runtime.h>

typedef __attribute__((ext_vector_type(8))) short bf16x8;
typedef __attribute__((ext_vector_type(4))) float f32x4;

#define D_MODEL 1024
#define T_LEN 2048
#define BATCH 2
#define N_HEADS 16
#define D_HEAD 64
#define WINDOW 256
#define N_STATE 128
#define D_FF 4096
#define N_CAT 4224   // 4*D_MODEL + N_STATE
#define LDQ 4352     // N_CAT padded
#define M_ROWS 4096  // B*T

static __device__ __forceinline__ float bf2f(unsigned short u) {
  union { unsigned int i; float f; } v; v.i = ((unsigned int)u) << 16; return v.f;
}
static __device__ __forceinline__ unsigned short f2bf(float f) {
  unsigned int x = __float_as_uint(f);
  return (unsigned short)((x + 0x7FFFu + ((x >> 16) & 1u)) >> 16);
}

static __device__ __forceinline__ void gl_lds16(const void* g, void* l) {
  __builtin_amdgcn_global_load_lds(
      (const __attribute__((address_space(1))) unsigned int*)g,
      (__attribute__((address_space(3))) unsigned int*)l, 16, 0, 0);
}

// ---------------------------------------------------------------------------
// Transpose + f32->bf16 convert: dst[(n_off+n)*ldd + k] = bf16(src[k*N + n])
// ---------------------------------------------------------------------------
__global__ __launch_bounds__(256) void transpose_cvt(
    const float* __restrict__ src, unsigned short* __restrict__ dst,
    int K, int N, int n_off, int ldd)
{
  __shared__ float tile[32][33];
  const int kt = blockIdx.x * 32, nt = blockIdx.y * 32;
  const int c = threadIdx.x & 31, r0 = threadIdx.x >> 5;
#pragma unroll
  for (int i = 0; i < 4; i++) {
    const int r = r0 + i * 8;
    tile[r][c] = src[(size_t)(kt + r) * N + nt + c];
  }
  __syncthreads();
#pragma unroll
  for (int i = 0; i < 4; i++) {
    const int r = r0 + i * 8;
    dst[(size_t)(n_off + nt + r) * ldd + kt + c] = f2bf(tile[c][r]);
  }
}

__global__ __launch_bounds__(256) void build_bcat(
    const float* __restrict__ bq, const float* __restrict__ bk,
    const float* __restrict__ bv, const float* __restrict__ bg,
    float* __restrict__ bcat)
{
  const int i = blockIdx.x * 256 + threadIdx.x;
  if (i < LDQ) {
    float v = 0.0f;
    if (i < 1024)      v = bq[i];
    else if (i < 2048) v = bk[i - 1024];
    else if (i < 3072) v = bv[i - 2048];
    else if (i < 4096) v = bg[i - 3072];
    bcat[i] = v;
  }
}

// ---------------------------------------------------------------------------
// LayerNorm: one block per row (1024 cols), bf16 output
// ---------------------------------------------------------------------------
__global__ __launch_bounds__(256) void ln_kernel(
    const float* __restrict__ x, const float* __restrict__ g,
    const float* __restrict__ b, unsigned short* __restrict__ out)
{
  const int row = blockIdx.x, tid = threadIdx.x;
  const float4 xv = ((const float4*)(x + (size_t)row * 1024))[tid];
  float s  = xv.x + xv.y + xv.z + xv.w;
  float s2 = xv.x * xv.x + xv.y * xv.y + xv.z * xv.z + xv.w * xv.w;
#pragma unroll
  for (int off = 32; off >= 1; off >>= 1) {
    s  += __shfl_down(s, off);
    s2 += __shfl_down(s2, off);
  }
  __shared__ float red[8];
  const int wave = tid >> 6;
  if ((tid & 63) == 0) { red[wave] = s; red[4 + wave] = s2; }
  __syncthreads();
  s  = red[0] + red[1] + red[2] + red[3];
  s2 = red[4] + red[5] + red[6] + red[7];
  const float mu = s * (1.0f / 1024.0f);
  const float rs = rsqrtf(s2 * (1.0f / 1024.0f) - mu * mu + 1e-5f);
  const float4 gv = ((const float4*)g)[tid];
  const float4 bv = ((const float4*)b)[tid];
  ushort4 o;
  o.x = f2bf((xv.x - mu) * rs * gv.x + bv.x);
  o.y = f2bf((xv.y - mu) * rs * gv.y + bv.y);
  o.z = f2bf((xv.z - mu) * rs * gv.z + bv.z);
  o.w = f2bf((xv.w - mu) * rs * gv.w + bv.w);
  ((ushort4*)(out + (size_t)row * 1024))[tid] = o;
}

// ---------------------------------------------------------------------------
// 256x256 GEMM, BK=64, 8 waves, double-buffered 128KB LDS, minimal 2-phase:
// stage(t+1) -> compute(t) -> __syncthreads (compiler-scheduled waits).
// Both-sides XOR swizzle (conflict-free ds_read_b128), XCD swizzle.
// C[r*ldc+c] = A[M,K] @ BT[N,K]^T + bias, ACT 0=none 2=gelu, bf16 out.
// ---------------------------------------------------------------------------
template<int ACT>
__global__ __launch_bounds__(512, 2) void gemm256(
    const unsigned short* __restrict__ A, const unsigned short* __restrict__ BT,
    const float* __restrict__ bias, unsigned short* __restrict__ C,
    int ldc, int K, int nbx)
{
  extern __shared__ char smem[];   // [2][A 32KB | B 32KB]
  const int nwg = gridDim.x;
  int bid = blockIdx.x;
  { // bijective XCD swizzle
    const int q = nwg >> 3, r = nwg & 7, x = bid & 7, o = bid >> 3;
    bid = (x < r ? x * (q + 1) : r * (q + 1) + (x - r) * q) + o;
  }
  const int m0 = (bid % nbx) * 256;
  const int n0 = (bid / nbx) * 256;

  const int tid = threadIdx.x, lane = tid & 63, wave = tid >> 6;
  const int wmi = wave >> 2, wni = wave & 3;
  const int l15 = lane & 15, lg = lane >> 4;
  const int NT = K >> 6;

  f32x4 acc[8][4];
#pragma unroll
  for (int i = 0; i < 8; i++)
#pragma unroll
    for (int j = 0; j < 4; j++) acc[i][j] = (f32x4){0.f, 0.f, 0.f, 0.f};

  // staging: LDS linear dest (phys p = hj*8192 + tid*16), source address
  // carries the inverse swizzle: logical row R = p>>7, col byte = (p&127)^((R&7)<<4)
  const char* srcA[4]; const char* srcB[4];
#pragma unroll
  for (int hj = 0; hj < 4; hj++) {
    const int p = hj * 8192 + tid * 16;
    const int R = p >> 7;
    const int cb = (p & 127) ^ ((R & 7) << 4);
    srcA[hj] = (const char*)A  + (size_t)(m0 + R) * (size_t)(K * 2) + cb;
    srcB[hj] = (const char*)BT + (size_t)(n0 + R) * (size_t)(K * 2) + cb;
  }

  // prologue: stage tile 0 into buf0
#pragma unroll
  for (int hj = 0; hj < 4; hj++) {
    gl_lds16(srcA[hj], smem + hj * 8192 + tid * 16);
    gl_lds16(srcB[hj], smem + 32768 + hj * 8192 + tid * 16);
  }
  __syncthreads();

  for (int t = 0; t < NT; ++t) {
    const char* cur = smem + (t & 1) * 65536;
    char* nxt = smem + ((t + 1) & 1) * 65536;
    if (t + 1 < NT) {
#pragma unroll
      for (int hj = 0; hj < 4; hj++) {
        gl_lds16(srcA[hj] + (size_t)(t + 1) * 128, nxt + hj * 8192 + tid * 16);
        gl_lds16(srcB[hj] + (size_t)(t + 1) * 128, nxt + 32768 + hj * 8192 + tid * 16);
      }
    }
    const char* cA = cur;
    const char* cB = cur + 32768;
    bf16x8 bfr[4][2], af[4][2];
#pragma unroll
    for (int nf = 0; nf < 4; nf++)
#pragma unroll
      for (int ks = 0; ks < 2; ks++) {
        const int R = wni * 64 + nf * 16 + l15;
        bfr[nf][ks] = *(const bf16x8*)(cB + (R << 7) + ((ks * 64 + lg * 16) ^ ((R & 7) << 4)));
      }
#pragma unroll
    for (int mh = 0; mh < 2; mh++) {
#pragma unroll
      for (int mf = 0; mf < 4; mf++)
#pragma unroll
        for (int ks = 0; ks < 2; ks++) {
          const int R = wmi * 128 + mh * 64 + mf * 16 + l15;
          af[mf][ks] = *(const bf16x8*)(cA + (R << 7) + ((ks * 64 + lg * 16) ^ ((R & 7) << 4)));
        }
#pragma unroll
      for (int mf = 0; mf < 4; mf++)
#pragma unroll
        for (int nf = 0; nf < 4; nf++)
#pragma unroll
          for (int ks = 0; ks < 2; ks++)
            acc[mh * 4 + mf][nf] = __builtin_amdgcn_mfma_f32_16x16x32_bf16(
                af[mf][ks], bfr[nf][ks], acc[mh * 4 + mf][nf], 0, 0, 0);
    }
    __syncthreads();
  }

  const int crow0 = m0 + wmi * 128 + lg * 4;
  const int ccol0 = n0 + wni * 64 + l15;
#pragma unroll
  for (int mf = 0; mf < 8; mf++)
#pragma unroll
    for (int r = 0; r < 4; r++) {
      const size_t rb = (size_t)(crow0 + mf * 16 + r) * ldc;
#pragma unroll
      for (int nf = 0; nf < 4; nf++) {
        const int col = ccol0 + nf * 16;
        float v = acc[mf][nf][r] + bias[col];
        if (ACT == 2) v = 0.5f * v * (1.0f + erff(v * 0.70710678118654752f));
        C[rb + col] = f2bf(v);
      }
    }
}

// ---------------------------------------------------------------------------
// Small GEMM: 128x64 tile, BK=64, single-buffer LDS (24KB, ~3 blk/CU),
// m97 2-barrier loop, XOR-swizzled LDS (conflict-free).
// ---------------------------------------------------------------------------
template<int ACT, bool OUT_BF16, bool RESID>
__global__ __launch_bounds__(256, 3) void gemm_bt(
    const unsigned short* __restrict__ A, const unsigned short* __restrict__ BT,
    const float* __restrict__ bias, const float* __restrict__ resid,
    void* __restrict__ Cout, int ldc, int K)
{
  __shared__ char As[16384];   // 128 rows x 128B
  __shared__ char Bs[8192];    // 64 rows x 128B
  const int m0 = blockIdx.x * 128, n0 = blockIdx.y * 64;
  const int tid = threadIdx.x, lane = tid & 63, wave = tid >> 6;
  const int l15 = lane & 15, lg = lane >> 4;
  const int wm = (wave & 1) * 64, wn = (wave >> 1) * 32;
  f32x4 acc[4][2];
#pragma unroll
  for (int i = 0; i < 4; i++)
#pragma unroll
    for (int j = 0; j < 2; j++) acc[i][j] = (f32x4){0.f, 0.f, 0.f, 0.f};

  const char* srcA[4]; const char* srcB[2];
#pragma unroll
  for (int j = 0; j < 4; j++) {
    const int p = j * 4096 + tid * 16;
    const int R = p >> 7;
    const int cb = (p & 127) ^ ((R & 7) << 4);
    srcA[j] = (const char*)A + (size_t)(m0 + R) * (size_t)(K * 2) + cb;
    if (j < 2) srcB[j] = (const char*)BT + (size_t)(n0 + R) * (size_t)(K * 2) + cb;
  }

  const int NT = K >> 6;
  for (int t = 0; t < NT; ++t) {
    __syncthreads();
#pragma unroll
    for (int j = 0; j < 4; j++)
      gl_lds16(srcA[j] + (size_t)t * 128, As + j * 4096 + tid * 16);
#pragma unroll
    for (int j = 0; j < 2; j++)
      gl_lds16(srcB[j] + (size_t)t * 128, Bs + j * 4096 + tid * 16);
    __syncthreads();
    bf16x8 af[4][2], bfr[2][2];
#pragma unroll
    for (int mf = 0; mf < 4; mf++)
#pragma unroll
      for (int ks = 0; ks < 2; ks++) {
        const int R = wm + mf * 16 + l15;
        af[mf][ks] = *(const bf16x8*)(As + (R << 7) + ((ks * 64 + lg * 16) ^ ((R & 7) << 4)));
      }
#pragma unroll
    for (int nf = 0; nf < 2; nf++)
#pragma unroll
      for (int ks = 0; ks < 2; ks++) {
        const int R = wn + nf * 16 + l15;
        bfr[nf][ks] = *(const bf16x8*)(Bs + (R << 7) + ((ks * 64 + lg * 16) ^ ((R & 7) << 4)));
      }
#pragma unroll
    for (int mf = 0; mf < 4; mf++)
#pragma unroll
      for (int nf = 0; nf < 2; nf++)
#pragma unroll
        for (int ks = 0; ks < 2; ks++)
          acc[mf][nf] = __builtin_amdgcn_mfma_f32_16x16x32_bf16(
              af[mf][ks], bfr[nf][ks], acc[mf][nf], 0, 0, 0);
  }

#pragma unroll
  for (int nf = 0; nf < 2; nf++) {
    const int col = n0 + wn + nf * 16 + l15;
    const float bv = bias ? bias[col] : 0.0f;
#pragma unroll
    for (int mf = 0; mf < 4; mf++) {
      const int rbase = m0 + wm + mf * 16 + lg * 4;
#pragma unroll
      for (int r = 0; r < 4; r++) {
        float v = acc[mf][nf][r] + bv;
        if (ACT == 2) v = 0.5f * v * (1.0f + erff(v * 0.70710678118654752f));
        const size_t idx = (size_t)(rbase + r) * ldc + col;
        if (RESID) v += resid[idx];
        if (OUT_BF16) ((unsigned short*)Cout)[idx] = f2bf(v);
        else          ((float*)Cout)[idx] = v;
      }
    }
  }
}

// ---------------------------------------------------------------------------
// Windowed causal attention, all-MFMA (r2-verified, LDQ stride)
// ---------------------------------------------------------------------------
__global__ __launch_bounds__(256) void attn_kernel(
    const unsigned short* __restrict__ qkvgu, unsigned short* __restrict__ ao)
{
  __shared__ float S[16][276];
  __shared__ unsigned short Vt[288][68];
  unsigned short* P = (unsigned short*)&S[0][0];

  const int bx = ((blockIdx.x & 7) << 4) | (blockIdx.x >> 3);
  const int q0 = bx * 16;
  const int h  = blockIdx.y;
  const int b  = blockIdx.z;
  const int tid = threadIdx.x, lane = tid & 63, wave = tid >> 6;
  const int l15 = lane & 15, lg = lane >> 4;
  const size_t rowbase = (size_t)b * T_LEN;

  {
    const int cg = (tid & 3) * 16;
    const int rr = tid >> 2;
#pragma unroll
    for (int j = 0; j < 5; j++) {
      const int row = j * 64 + rr;
      if (row < 288) {
        const int vrow = q0 - 256 + row;
        uint4 d0 = {0u, 0u, 0u, 0u}, d1 = {0u, 0u, 0u, 0u};
        if (vrow >= 0 && row < 272) {
          const unsigned short* vp = qkvgu + (rowbase + vrow) * LDQ + 2048 + h * 64 + cg;
          d0 = *(const uint4*)vp;
          d1 = *(const uint4*)(vp + 8);
        }
        unsigned short* wp = &Vt[row][cg];
        ((uint2*)wp)[0] = make_uint2(d0.x, d0.y);
        ((uint2*)wp)[1] = make_uint2(d0.z, d0.w);
        ((uint2*)wp)[2] = make_uint2(d1.x, d1.y);
        ((uint2*)wp)[3] = make_uint2(d1.z, d1.w);
      }
    }
  }

  {
    const unsigned short* qp = qkvgu + (rowbase + q0 + l15) * LDQ + h * 64 + lg * 8;
    const bf16x8 aq0 = *(const bf16x8*)qp;
    const bf16x8 aq1 = *(const bf16x8*)(qp + 32);
    for (int kt = wave; kt < 17; kt += 4) {
      const int kbase = q0 - 256 + kt * 16;
      const int krow = kbase + l15;
      const int krc = krow < 0 ? 0 : krow;
      const unsigned short* kp = qkvgu + (rowbase + krc) * LDQ + 1024 + h * 64 + lg * 8;
      const bf16x8 bk0 = *(const bf16x8*)kp;
      const bf16x8 bk1 = *(const bf16x8*)(kp + 32);
      f32x4 sacc = (f32x4){0.f, 0.f, 0.f, 0.f};
      sacc = __builtin_amdgcn_mfma_f32_16x16x32_bf16(aq0, bk0, sacc, 0, 0, 0);
      sacc = __builtin_amdgcn_mfma_f32_16x16x32_bf16(aq1, bk1, sacc, 0, 0, 0);
#pragma unroll
      for (int r = 0; r < 4; r++) {
        const int qi = q0 + lg * 4 + r;
        const int kj = kbase + l15;
        const bool ok = (kj >= 0) && (kj <= qi) && (qi - kj < WINDOW);
        S[lg * 4 + r][kt * 16 + l15] = ok ? sacc[r] * 0.125f : -1e30f;
      }
    }
  }
  __syncthreads();

  {
    const int q = tid >> 4, sub = tid & 15;
    float mx = -1e30f;
    for (int c = sub; c < 272; c += 16) mx = fmaxf(mx, S[q][c]);
#pragma unroll
    for (int off = 8; off >= 1; off >>= 1) mx = fmaxf(mx, __shfl_xor(mx, off));
    float sum = 0.f;
    for (int c = sub; c < 272; c += 16) sum += __expf(S[q][c] - mx);
#pragma unroll
    for (int off = 8; off >= 1; off >>= 1) sum += __shfl_xor(sum, off);
    const float inv = 1.0f / sum;
    unsigned short* Prow = P + q * 552;
    for (int c = sub; c < 288; c += 16) {
      const float pv = (c < 272) ? __expf(S[q][c] - mx) * inv : 0.0f;
      Prow[c] = f2bf(pv);
    }
  }
  __syncthreads();

  {
    f32x4 oacc = (f32x4){0.f, 0.f, 0.f, 0.f};
    const int dn = wave * 16 + l15;
#pragma unroll
    for (int ks = 0; ks < 9; ks++) {
      const bf16x8 pa = *(const bf16x8*)(P + l15 * 552 + ks * 32 + lg * 8);
      bf16x8 vb;
      const int kb = ks * 32 + lg * 8;
#pragma unroll
      for (int j = 0; j < 8; j++) ((unsigned short*)&vb)[j] = Vt[kb + j][dn];
      oacc = __builtin_amdgcn_mfma_f32_16x16x32_bf16(pa, vb, oacc, 0, 0, 0);
    }
#pragma unroll
    for (int r = 0; r < 4; r++)
      ao[(rowbase + q0 + lg * 4 + r) * D_MODEL + h * 64 + dn] = f2bf(oacc[r]);
  }
}

// ---------------------------------------------------------------------------
// Chunked SSM scan (|A|<0.1 => A^512 underflows; carry fixup self-terminates)
// ---------------------------------------------------------------------------
__global__ __launch_bounds__(1024) void scan_kernel(
    const unsigned short* __restrict__ qkvgu, const float* __restrict__ Avec,
    const float* __restrict__ s0, unsigned short* __restrict__ states,
    float* __restrict__ out_state)
{
  __shared__ float finals[4][256];
  const int tid = threadIdx.x;
  const int bn = tid & 255;
  const int b = bn >> 7, n = bn & 127;
  const int c = tid >> 8;
  const float a = Avec[n];
  float s = (c == 0) ? s0[bn] : 0.0f;
  const size_t ubase = (size_t)b * T_LEN * LDQ + 4096 + n;
  unsigned short* sp = states + (size_t)b * T_LEN * N_STATE + n;
  const int t0 = c * 512;
#pragma unroll 8
  for (int t = t0; t < t0 + 512; t++) {
    s = fmaf(a, s, bf2f(qkvgu[ubase + (size_t)t * LDQ]));
    sp[(size_t)t * N_STATE] = f2bf(s);
  }
  finals[c][bn] = s;
  if (c == 3) out_state[bn] = s;
  __syncthreads();
  if (c > 0) {
    const float carry = finals[c - 1][bn];
    float f = a;
    for (int t = t0; t < t0 + 512; t++) {
      if (f == 0.0f) break;
      const float v = bf2f(sp[(size_t)t * N_STATE]) + f * carry;
      sp[(size_t)t * N_STATE] = f2bf(v);
      f *= a;
    }
  }
}

// ---------------------------------------------------------------------------
// Gated fusion: out = x + g*attn + (1-g)*ssm,  g = sigmoid(xg)
// ---------------------------------------------------------------------------
__global__ __launch_bounds__(256) void fusion_kernel(
    const float* __restrict__ x, const unsigned short* __restrict__ qkvgu,
    const unsigned short* __restrict__ attn, const unsigned short* __restrict__ ssm,
    float* __restrict__ out)
{
  const int i = blockIdx.x * 256 + threadIdx.x;
  const size_t e4 = (size_t)i * 4;
  const int row = i >> 8;
  const int col = (i & 255) * 4;
  const float4 xv = *(const float4*)(x + e4);
  const ushort4 au = *(const ushort4*)(attn + e4);
  const ushort4 su = *(const ushort4*)(ssm + e4);
  const ushort4 gu = *(const ushort4*)(qkvgu + (size_t)row * LDQ + 3072 + col);
  float4 o;
  const float g0 = 1.0f / (1.0f + __expf(-bf2f(gu.x)));
  const float g1 = 1.0f / (1.0f + __expf(-bf2f(gu.y)));
  const float g2 = 1.0f / (1.0f + __expf(-bf2f(gu.z)));
  const float g3 = 1.0f / (1.0f + __expf(-bf2f(gu.w)));
  o.x = xv.x + g0 * bf2f(au.x) + (1.0f - g0) * bf2f(su.x);
  o.y = xv.y + g1 * bf2f(au.y) + (1.0f - g1) * bf2f(su.y);
  o.z = xv.z + g2 * bf2f(au.z) + (1.0f - g2) * bf2f(su.z);
  o.w = xv.w + g3 * bf2f(au.w) + (1.0f - g3) * bf2f(su.w);
  *(float4*)(out + e4) = o;
}

// ---------------------------------------------------------------------------
extern "C" void kernel_launch(void* const* d_in, const int* in_sizes, int n_in,
                              void* d_out, int out_size, void* d_ws, size_t ws_size,
                              hipStream_t stream)
{
  const float* x     = (const float*)d_in[0];
  const float* ssm0  = (const float*)d_in[1];
  const float* ln1_g = (const float*)d_in[2];
  const float* ln1_b = (const float*)d_in[3];
  const float* wq    = (const float*)d_in[4];
  const float* bq    = (const float*)d_in[5];
  const float* wk    = (const float*)d_in[6];
  const float* bk    = (const float*)d_in[7];
  const float* wv    = (const float*)d_in[8];
  const float* bv    = (const float*)d_in[9];
  const float* wo    = (const float*)d_in[10];
  const float* bo    = (const float*)d_in[11];
  const float* wg    = (const float*)d_in[12];
  const float* bg    = (const float*)d_in[13];
  const float* Av    = (const float*)d_in[14];
  const float* Bw    = (const float*)d_in[15];
  const float* Cw    = (const float*)d_in[16];
  const float* ln2_g = (const float*)d_in[17];
  const float* ln2_b = (const float*)d_in[18];
  const float* w1    = (const float*)d_in[19];
  const float* b1    = (const float*)d_in[20];
  const float* w2    = (const float*)d_in[21];
  const float* b2    = (const float*)d_in[22];

  char* p = (char*)d_ws;
  auto take = [&](size_t bytes) { char* q = p; p += (bytes + 255) & ~(size_t)255; return q; };
  unsigned short* WcatT  = (unsigned short*)take((size_t)LDQ * 1024 * 2);
  unsigned short* woT    = (unsigned short*)take((size_t)1024 * 1024 * 2);
  unsigned short* CwT    = (unsigned short*)take((size_t)1024 * 128 * 2);
  unsigned short* w1T    = (unsigned short*)take((size_t)4096 * 1024 * 2);
  unsigned short* w2T    = (unsigned short*)take((size_t)1024 * 4096 * 2);
  float*          bcat   = (float*)take((size_t)LDQ * 4);
  unsigned short* xn     = (unsigned short*)take((size_t)M_ROWS * 1024 * 2);
  unsigned short* qkvgu  = (unsigned short*)take((size_t)M_ROWS * LDQ * 2);
  unsigned short* ao     = (unsigned short*)take((size_t)M_ROWS * 1024 * 2);
  unsigned short* states = (unsigned short*)take((size_t)M_ROWS * N_STATE * 2);
  unsigned short* attn_o = (unsigned short*)take((size_t)M_ROWS * 1024 * 2);
  unsigned short* ssm_o  = (unsigned short*)take((size_t)M_ROWS * 1024 * 2);
  unsigned short* hbuf   = qkvgu;   // alias: qkvgu dead after fusion

  float* outx = (float*)d_out;
  float* out_state = outx + (size_t)M_ROWS * 1024;

  const bool big_ok =
      hipFuncSetAttribute((const void*)gemm256<0>,
                          hipFuncAttributeMaxDynamicSharedMemorySize, 131072) == hipSuccess &&
      hipFuncSetAttribute((const void*)gemm256<2>,
                          hipFuncAttributeMaxDynamicSharedMemorySize, 131072) == hipSuccess;

  // --- weight prep (bf16, transposed) ---
  transpose_cvt<<<dim3(32, 32), 256, 0, stream>>>(wq, WcatT, 1024, 1024, 0, 1024);
  transpose_cvt<<<dim3(32, 32), 256, 0, stream>>>(wk, WcatT, 1024, 1024, 1024, 1024);
  transpose_cvt<<<dim3(32, 32), 256, 0, stream>>>(wv, WcatT, 1024, 1024, 2048, 1024);
  transpose_cvt<<<dim3(32, 32), 256, 0, stream>>>(wg, WcatT, 1024, 1024, 3072, 1024);
  transpose_cvt<<<dim3(32, 4), 256, 0, stream>>>(Bw, WcatT, 1024, 128, 4096, 1024);
  transpose_cvt<<<dim3(32, 32), 256, 0, stream>>>(wo, woT, 1024, 1024, 0, 1024);
  transpose_cvt<<<dim3(4, 32), 256, 0, stream>>>(Cw, CwT, 128, 1024, 0, 128);
  transpose_cvt<<<dim3(32, 128), 256, 0, stream>>>(w1, w1T, 1024, 4096, 0, 1024);
  transpose_cvt<<<dim3(128, 32), 256, 0, stream>>>(w2, w2T, 4096, 1024, 0, 4096);
  build_bcat<<<17, 256, 0, stream>>>(bq, bk, bv, bg, bcat);

  // --- forward ---
  ln_kernel<<<M_ROWS, 256, 0, stream>>>(x, ln1_g, ln1_b, xn);
  // mega projection: cols [0,4096) via 256-tile (grid 256 = 1 round/CU),
  // cols [4096,4352) via small GEMM
  if (big_ok)
    gemm256<0><<<256, 512, 131072, stream>>>(xn, WcatT, bcat, qkvgu, LDQ, 1024, 16);
  else
    gemm_bt<0, true, false><<<dim3(32, 64), 256, 0, stream>>>(
        xn, WcatT, bcat, nullptr, qkvgu, LDQ, 1024);
  gemm_bt<0, true, false><<<dim3(32, 4), 256, 0, stream>>>(
      xn, WcatT + (size_t)4096 * 1024, bcat + 4096, nullptr, qkvgu + 4096, LDQ, 1024);
  attn_kernel<<<dim3(128, 16, 2), 256, 0, stream>>>(qkvgu, ao);
  scan_kernel<<<1, 1024, 0, stream>>>(qkvgu, Av, ssm0, states, out_state);
  gemm_bt<0, true, false><<<dim3(32, 16), 256, 0, stream>>>(
      ao, woT, bo, nullptr, attn_o, 1024, 1024);
  gemm_bt<0, true, false><<<dim3(32, 16), 256, 0, stream>>>(
      states, CwT, nullptr, nullptr, ssm_o, 1024, 128);
  fusion_kernel<<<4096, 256, 0, stream>>>(x, qkvgu, attn_o, ssm_o, outx);
  ln_kernel<<<M_ROWS, 256, 0, stream>>>(outx, ln2_g, ln2_b, xn);
  if (big_ok)
    gemm256<2><<<256, 512, 131072, stream>>>(xn, w1T, b1, hbuf, 4096, 1024, 16);
  else
    gemm_bt<2, true, false><<<dim3(32, 64), 256, 0, stream>>>(
        xn, w1T, b1, nullptr, hbuf, 4096, 1024);
  gemm_bt<0, false, true><<<dim3(32, 16), 256, 0, stream>>>(
      hbuf, w2T, b2, outx, outx, 1024, 4096);
}

// Round 5
// 409.129 us; speedup vs baseline: 1.0955x; 1.0029x over previous
//
#include <hip/hip_runtime.h>

typedef __attribute__((ext_vector_type(8))) short bf16x8;
typedef __attribute__((ext_vector_type(4))) float f32x4;

#define D_MODEL 1024
#define T_LEN 2048
#define BATCH 2
#define N_HEADS 16
#define D_HEAD 64
#define WINDOW 256
#define N_STATE 128
#define D_FF 4096
#define N_CAT 4224   // 4*D_MODEL + N_STATE
#define LDQ 4352     // N_CAT padded
#define M_ROWS 4096  // B*T

static __device__ __forceinline__ float bf2f(unsigned short u) {
  union { unsigned int i; float f; } v; v.i = ((unsigned int)u) << 16; return v.f;
}
static __device__ __forceinline__ unsigned short f2bf(float f) {
  unsigned int x = __float_as_uint(f);
  return (unsigned short)((x + 0x7FFFu + ((x >> 16) & 1u)) >> 16);
}

static __device__ __forceinline__ void gl_lds16(const void* g, void* l) {
  __builtin_amdgcn_global_load_lds(
      (const __attribute__((address_space(1))) unsigned int*)g,
      (__attribute__((address_space(3))) unsigned int*)l, 16, 0, 0);
}

// ---------------------------------------------------------------------------
// Transpose + f32->bf16 convert: dst[(n_off+n)*ldd + k] = bf16(src[k*N + n])
// ---------------------------------------------------------------------------
__global__ __launch_bounds__(256) void transpose_cvt(
    const float* __restrict__ src, unsigned short* __restrict__ dst,
    int K, int N, int n_off, int ldd)
{
  __shared__ float tile[32][33];
  const int kt = blockIdx.x * 32, nt = blockIdx.y * 32;
  const int c = threadIdx.x & 31, r0 = threadIdx.x >> 5;
#pragma unroll
  for (int i = 0; i < 4; i++) {
    const int r = r0 + i * 8;
    tile[r][c] = src[(size_t)(kt + r) * N + nt + c];
  }
  __syncthreads();
#pragma unroll
  for (int i = 0; i < 4; i++) {
    const int r = r0 + i * 8;
    dst[(size_t)(n_off + nt + r) * ldd + kt + c] = f2bf(tile[c][r]);
  }
}

__global__ __launch_bounds__(256) void build_bcat(
    const float* __restrict__ bq, const float* __restrict__ bk,
    const float* __restrict__ bv, const float* __restrict__ bg,
    float* __restrict__ bcat)
{
  const int i = blockIdx.x * 256 + threadIdx.x;
  if (i < LDQ) {
    float v = 0.0f;
    if (i < 1024)      v = bq[i];
    else if (i < 2048) v = bk[i - 1024];
    else if (i < 3072) v = bv[i - 2048];
    else if (i < 4096) v = bg[i - 3072];
    bcat[i] = v;
  }
}

// ---------------------------------------------------------------------------
// LayerNorm: one block per row (1024 cols), bf16 output
// ---------------------------------------------------------------------------
__global__ __launch_bounds__(256) void ln_kernel(
    const float* __restrict__ x, const float* __restrict__ g,
    const float* __restrict__ b, unsigned short* __restrict__ out)
{
  const int row = blockIdx.x, tid = threadIdx.x;
  const float4 xv = ((const float4*)(x + (size_t)row * 1024))[tid];
  float s  = xv.x + xv.y + xv.z + xv.w;
  float s2 = xv.x * xv.x + xv.y * xv.y + xv.z * xv.z + xv.w * xv.w;
#pragma unroll
  for (int off = 32; off >= 1; off >>= 1) {
    s  += __shfl_down(s, off);
    s2 += __shfl_down(s2, off);
  }
  __shared__ float red[8];
  const int wave = tid >> 6;
  if ((tid & 63) == 0) { red[wave] = s; red[4 + wave] = s2; }
  __syncthreads();
  s  = red[0] + red[1] + red[2] + red[3];
  s2 = red[4] + red[5] + red[6] + red[7];
  const float mu = s * (1.0f / 1024.0f);
  const float rs = rsqrtf(s2 * (1.0f / 1024.0f) - mu * mu + 1e-5f);
  const float4 gv = ((const float4*)g)[tid];
  const float4 bv = ((const float4*)b)[tid];
  ushort4 o;
  o.x = f2bf((xv.x - mu) * rs * gv.x + bv.x);
  o.y = f2bf((xv.y - mu) * rs * gv.y + bv.y);
  o.z = f2bf((xv.z - mu) * rs * gv.z + bv.z);
  o.w = f2bf((xv.w - mu) * rs * gv.w + bv.w);
  ((ushort4*)(out + (size_t)row * 1024))[tid] = o;
}

// ---------------------------------------------------------------------------
// 256x256 GEMM, BK=64, 8 waves (2Mx4N), 128KB LDS (2 buffers), m201 8-phase
// schedule: per K-tile 4 quadrant-phases, 1 half-tile (2 gl_lds16) staged per
// phase, staging runs TWO tiles ahead into the dead regions of the buffer
// being computed; counted vmcnt(6) once per K-tile (never 0 mid-loop).
// Ledger: at t.ph4 vmcnt(6) leaves {A(t+2)q0q2, B(t+2)h0, B(t+2)h1} in
// flight; everything tile t+1 reads is strictly older => landed.
// ---------------------------------------------------------------------------
__device__ __forceinline__ void lda_q(const char* bufA, int wmi, int mh,
                                      int l15, int lg, bf16x8 (&af)[4][2]) {
#pragma unroll
  for (int mf = 0; mf < 4; mf++)
#pragma unroll
    for (int ks = 0; ks < 2; ks++) {
      const int R = wmi * 128 + mh * 64 + mf * 16 + l15;
      af[mf][ks] = *(const bf16x8*)(bufA + (R << 7) + ((ks * 64 + lg * 16) ^ ((R & 7) << 4)));
    }
}
__device__ __forceinline__ void ldb_q(const char* bufB, int wni, int nh,
                                      int l15, int lg, bf16x8 (&bf)[2][2]) {
#pragma unroll
  for (int nf = 0; nf < 2; nf++)
#pragma unroll
    for (int ks = 0; ks < 2; ks++) {
      const int R = wni * 64 + nh * 32 + nf * 16 + l15;
      bf[nf][ks] = *(const bf16x8*)(bufB + (R << 7) + ((ks * 64 + lg * 16) ^ ((R & 7) << 4)));
    }
}
__device__ __forceinline__ void mfma_q(f32x4 (&acc)[8][4], const bf16x8 (&af)[4][2],
                                       const bf16x8 (&bf)[2][2], int mh, int nh) {
  __builtin_amdgcn_s_barrier();
  asm volatile("s_waitcnt lgkmcnt(0)" ::: "memory");
  __builtin_amdgcn_sched_barrier(0);
  __builtin_amdgcn_s_setprio(1);
#pragma unroll
  for (int mf = 0; mf < 4; mf++)
#pragma unroll
    for (int nf = 0; nf < 2; nf++)
#pragma unroll
      for (int ks = 0; ks < 2; ks++)
        acc[mh * 4 + mf][nh * 2 + nf] = __builtin_amdgcn_mfma_f32_16x16x32_bf16(
            af[mf][ks], bf[nf][ks], acc[mh * 4 + mf][nh * 2 + nf], 0, 0, 0);
  __builtin_amdgcn_s_setprio(0);
  __builtin_amdgcn_s_barrier();
}

template<int ACT>
__global__ __launch_bounds__(512, 2) void gemm256(
    const unsigned short* __restrict__ A, const unsigned short* __restrict__ BT,
    const float* __restrict__ bias, unsigned short* __restrict__ C,
    int ldc, int K, int nbx)
{
  extern __shared__ char smem[];   // buf0 @0, buf1 @65536; each: A 32KB | B 32KB
  const int nwg = gridDim.x;
  int bid = blockIdx.x;
  { // bijective XCD swizzle
    const int q = nwg >> 3, r = nwg & 7, x = bid & 7, o = bid >> 3;
    bid = (x < r ? x * (q + 1) : r * (q + 1) + (x - r) * q) + o;
  }
  const int m0 = (bid % nbx) * 256;
  const int n0 = (bid / nbx) * 256;

  const int tid = threadIdx.x, lane = tid & 63, wave = tid >> 6;
  const int wmi = wave >> 2, wni = wave & 3;
  const int l15 = lane & 15, lg = lane >> 4;
  const int NT = K >> 6;   // must be even (16 or more)

  f32x4 acc[8][4];
#pragma unroll
  for (int i = 0; i < 8; i++)
#pragma unroll
    for (int j = 0; j < 4; j++) acc[i][j] = (f32x4){0.f, 0.f, 0.f, 0.f};

  // quarter staging sources (64 rows each), inverse-swizzled global addresses
  const char* srcA[4]; const char* srcB[4];
#pragma unroll
  for (int qd = 0; qd < 4; qd++) {
    const int p = qd * 8192 + tid * 16;
    const int R = p >> 7;
    const int cb = (p & 127) ^ ((R & 7) << 4);
    srcA[qd] = (const char*)A  + (size_t)(m0 + R) * (size_t)(K * 2) + cb;
    srcB[qd] = (const char*)BT + (size_t)(n0 + R) * (size_t)(K * 2) + cb;
  }
  char* const buf0 = smem;
  char* const buf1 = smem + 65536;

#define SA(qd, kt, buf) gl_lds16(srcA[qd] + (size_t)(kt) * 128, (buf) + (qd) * 8192 + tid * 16)
#define SB(qd, kt, buf) gl_lds16(srcB[qd] + (size_t)(kt) * 128, (buf) + 32768 + (qd) * 8192 + tid * 16)

  // prologue: tile0 fully (order: Aq0q2, Bh0, Bh1, Aq1q3), tile1 first 3 halves
  SA(0, 0, buf0); SA(2, 0, buf0);
  SB(0, 0, buf0); SB(1, 0, buf0);
  SB(2, 0, buf0); SB(3, 0, buf0);
  SA(1, 0, buf0); SA(3, 0, buf0);
  SA(0, 1, buf1); SA(2, 1, buf1);
  SB(0, 1, buf1); SB(1, 1, buf1);
  SB(2, 1, buf1); SB(3, 1, buf1);
  asm volatile("s_waitcnt vmcnt(6)" ::: "memory");   // tile0 resident
  __builtin_amdgcn_s_barrier();

  bf16x8 af[4][2], bf0[2][2], bf1[2][2];

#define ITER(t, CUR, NXT) do {                                                \
    /* ph1: reads Aq(2*wmi), B first-halves; stage A(t+1)q1q3 -> NXT */       \
    lda_q((CUR), wmi, 0, l15, lg, af);                                        \
    ldb_q((CUR) + 32768, wni, 0, l15, lg, bf0);                               \
    if ((t) + 1 < NT) { SA(1, (t) + 1, NXT); SA(3, (t) + 1, NXT); }           \
    mfma_q(acc, af, bf0, 0, 0);                                               \
    /* ph2: reads B second-halves; stage A(t+2)q0q2 -> CUR (Aq0q2 dead) */    \
    ldb_q((CUR) + 32768, wni, 1, l15, lg, bf1);                               \
    if ((t) + 2 < NT) { SA(0, (t) + 2, CUR); SA(2, (t) + 2, CUR); }           \
    mfma_q(acc, af, bf1, 0, 1);                                               \
    /* ph3: reads Aq1q3; stage B(t+2)h0 -> CUR (B fully dead after ph2) */    \
    lda_q((CUR), wmi, 1, l15, lg, af);                                        \
    if ((t) + 2 < NT) { SB(0, (t) + 2, CUR); SB(1, (t) + 2, CUR); }           \
    mfma_q(acc, af, bf0, 1, 0);                                               \
    /* ph4: stage B(t+2)h1 -> CUR; counted vmcnt (tail: drain) */             \
    if ((t) + 2 < NT) {                                                       \
      SB(2, (t) + 2, CUR); SB(3, (t) + 2, CUR);                               \
      asm volatile("s_waitcnt vmcnt(6)" ::: "memory");                        \
    } else {                                                                  \
      asm volatile("s_waitcnt vmcnt(0)" ::: "memory");                        \
    }                                                                         \
    mfma_q(acc, af, bf1, 1, 1);                                               \
  } while (0)

  for (int t = 0; t < NT; t += 2) {
    ITER(t, buf0, buf1);
    ITER(t + 1, buf1, buf0);
  }
#undef ITER
#undef SA
#undef SB

  const int crow0 = m0 + wmi * 128 + lg * 4;
  const int ccol0 = n0 + wni * 64 + l15;
#pragma unroll
  for (int mf = 0; mf < 8; mf++)
#pragma unroll
    for (int r = 0; r < 4; r++) {
      const size_t rb = (size_t)(crow0 + mf * 16 + r) * ldc;
#pragma unroll
      for (int nf = 0; nf < 4; nf++) {
        const int col = ccol0 + nf * 16;
        float v = acc[mf][nf][r] + bias[col];
        if (ACT == 2) v = 0.5f * v * (1.0f + erff(v * 0.70710678118654752f));
        C[rb + col] = f2bf(v);
      }
    }
}

// ---------------------------------------------------------------------------
// Small GEMM: 128x64 tile, BK=64, single-buffer LDS, m97 2-barrier loop,
// XOR-swizzled LDS (conflict-free).
// ---------------------------------------------------------------------------
template<int ACT, bool OUT_BF16, bool RESID>
__global__ __launch_bounds__(256, 3) void gemm_bt(
    const unsigned short* __restrict__ A, const unsigned short* __restrict__ BT,
    const float* __restrict__ bias, const float* __restrict__ resid,
    void* __restrict__ Cout, int ldc, int K)
{
  __shared__ char As[16384];
  __shared__ char Bs[8192];
  const int m0 = blockIdx.x * 128, n0 = blockIdx.y * 64;
  const int tid = threadIdx.x, lane = tid & 63, wave = tid >> 6;
  const int l15 = lane & 15, lg = lane >> 4;
  const int wm = (wave & 1) * 64, wn = (wave >> 1) * 32;
  f32x4 acc[4][2];
#pragma unroll
  for (int i = 0; i < 4; i++)
#pragma unroll
    for (int j = 0; j < 2; j++) acc[i][j] = (f32x4){0.f, 0.f, 0.f, 0.f};

  const char* srcA[4]; const char* srcB[2];
#pragma unroll
  for (int j = 0; j < 4; j++) {
    const int p = j * 4096 + tid * 16;
    const int R = p >> 7;
    const int cb = (p & 127) ^ ((R & 7) << 4);
    srcA[j] = (const char*)A + (size_t)(m0 + R) * (size_t)(K * 2) + cb;
    if (j < 2) srcB[j] = (const char*)BT + (size_t)(n0 + R) * (size_t)(K * 2) + cb;
  }

  const int NT = K >> 6;
  for (int t = 0; t < NT; ++t) {
    __syncthreads();
#pragma unroll
    for (int j = 0; j < 4; j++)
      gl_lds16(srcA[j] + (size_t)t * 128, As + j * 4096 + tid * 16);
#pragma unroll
    for (int j = 0; j < 2; j++)
      gl_lds16(srcB[j] + (size_t)t * 128, Bs + j * 4096 + tid * 16);
    __syncthreads();
    bf16x8 af[4][2], bfr[2][2];
#pragma unroll
    for (int mf = 0; mf < 4; mf++)
#pragma unroll
      for (int ks = 0; ks < 2; ks++) {
        const int R = wm + mf * 16 + l15;
        af[mf][ks] = *(const bf16x8*)(As + (R << 7) + ((ks * 64 + lg * 16) ^ ((R & 7) << 4)));
      }
#pragma unroll
    for (int nf = 0; nf < 2; nf++)
#pragma unroll
      for (int ks = 0; ks < 2; ks++) {
        const int R = wn + nf * 16 + l15;
        bfr[nf][ks] = *(const bf16x8*)(Bs + (R << 7) + ((ks * 64 + lg * 16) ^ ((R & 7) << 4)));
      }
#pragma unroll
    for (int mf = 0; mf < 4; mf++)
#pragma unroll
      for (int nf = 0; nf < 2; nf++)
#pragma unroll
        for (int ks = 0; ks < 2; ks++)
          acc[mf][nf] = __builtin_amdgcn_mfma_f32_16x16x32_bf16(
              af[mf][ks], bfr[nf][ks], acc[mf][nf], 0, 0, 0);
  }

#pragma unroll
  for (int nf = 0; nf < 2; nf++) {
    const int col = n0 + wn + nf * 16 + l15;
    const float bv = bias ? bias[col] : 0.0f;
#pragma unroll
    for (int mf = 0; mf < 4; mf++) {
      const int rbase = m0 + wm + mf * 16 + lg * 4;
#pragma unroll
      for (int r = 0; r < 4; r++) {
        float v = acc[mf][nf][r] + bv;
        if (ACT == 2) v = 0.5f * v * (1.0f + erff(v * 0.70710678118654752f));
        const size_t idx = (size_t)(rbase + r) * ldc + col;
        if (RESID) v += resid[idx];
        if (OUT_BF16) ((unsigned short*)Cout)[idx] = f2bf(v);
        else          ((float*)Cout)[idx] = v;
      }
    }
  }
}

// ---------------------------------------------------------------------------
// Windowed causal attention, all-MFMA (r2-verified, LDQ stride)
// ---------------------------------------------------------------------------
__global__ __launch_bounds__(256) void attn_kernel(
    const unsigned short* __restrict__ qkvgu, unsigned short* __restrict__ ao)
{
  __shared__ float S[16][276];
  __shared__ unsigned short Vt[288][68];
  unsigned short* P = (unsigned short*)&S[0][0];

  const int bx = ((blockIdx.x & 7) << 4) | (blockIdx.x >> 3);
  const int q0 = bx * 16;
  const int h  = blockIdx.y;
  const int b  = blockIdx.z;
  const int tid = threadIdx.x, lane = tid & 63, wave = tid >> 6;
  const int l15 = lane & 15, lg = lane >> 4;
  const size_t rowbase = (size_t)b * T_LEN;

  {
    const int cg = (tid & 3) * 16;
    const int rr = tid >> 2;
#pragma unroll
    for (int j = 0; j < 5; j++) {
      const int row = j * 64 + rr;
      if (row < 288) {
        const int vrow = q0 - 256 + row;
        uint4 d0 = {0u, 0u, 0u, 0u}, d1 = {0u, 0u, 0u, 0u};
        if (vrow >= 0 && row < 272) {
          const unsigned short* vp = qkvgu + (rowbase + vrow) * LDQ + 2048 + h * 64 + cg;
          d0 = *(const uint4*)vp;
          d1 = *(const uint4*)(vp + 8);
        }
        unsigned short* wp = &Vt[row][cg];
        ((uint2*)wp)[0] = make_uint2(d0.x, d0.y);
        ((uint2*)wp)[1] = make_uint2(d0.z, d0.w);
        ((uint2*)wp)[2] = make_uint2(d1.x, d1.y);
        ((uint2*)wp)[3] = make_uint2(d1.z, d1.w);
      }
    }
  }

  {
    const unsigned short* qp = qkvgu + (rowbase + q0 + l15) * LDQ + h * 64 + lg * 8;
    const bf16x8 aq0 = *(const bf16x8*)qp;
    const bf16x8 aq1 = *(const bf16x8*)(qp + 32);
    for (int kt = wave; kt < 17; kt += 4) {
      const int kbase = q0 - 256 + kt * 16;
      const int krow = kbase + l15;
      const int krc = krow < 0 ? 0 : krow;
      const unsigned short* kp = qkvgu + (rowbase + krc) * LDQ + 1024 + h * 64 + lg * 8;
      const bf16x8 bk0 = *(const bf16x8*)kp;
      const bf16x8 bk1 = *(const bf16x8*)(kp + 32);
      f32x4 sacc = (f32x4){0.f, 0.f, 0.f, 0.f};
      sacc = __builtin_amdgcn_mfma_f32_16x16x32_bf16(aq0, bk0, sacc, 0, 0, 0);
      sacc = __builtin_amdgcn_mfma_f32_16x16x32_bf16(aq1, bk1, sacc, 0, 0, 0);
#pragma unroll
      for (int r = 0; r < 4; r++) {
        const int qi = q0 + lg * 4 + r;
        const int kj = kbase + l15;
        const bool ok = (kj >= 0) && (kj <= qi) && (qi - kj < WINDOW);
        S[lg * 4 + r][kt * 16 + l15] = ok ? sacc[r] * 0.125f : -1e30f;
      }
    }
  }
  __syncthreads();

  {
    const int q = tid >> 4, sub = tid & 15;
    float mx = -1e30f;
    for (int c = sub; c < 272; c += 16) mx = fmaxf(mx, S[q][c]);
#pragma unroll
    for (int off = 8; off >= 1; off >>= 1) mx = fmaxf(mx, __shfl_xor(mx, off));
    float sum = 0.f;
    for (int c = sub; c < 272; c += 16) sum += __expf(S[q][c] - mx);
#pragma unroll
    for (int off = 8; off >= 1; off >>= 1) sum += __shfl_xor(sum, off);
    const float inv = 1.0f / sum;
    unsigned short* Prow = P + q * 552;
    for (int c = sub; c < 288; c += 16) {
      const float pv = (c < 272) ? __expf(S[q][c] - mx) * inv : 0.0f;
      Prow[c] = f2bf(pv);
    }
  }
  __syncthreads();

  {
    f32x4 oacc = (f32x4){0.f, 0.f, 0.f, 0.f};
    const int dn = wave * 16 + l15;
#pragma unroll
    for (int ks = 0; ks < 9; ks++) {
      const bf16x8 pa = *(const bf16x8*)(P + l15 * 552 + ks * 32 + lg * 8);
      bf16x8 vb;
      const int kb = ks * 32 + lg * 8;
#pragma unroll
      for (int j = 0; j < 8; j++) ((unsigned short*)&vb)[j] = Vt[kb + j][dn];
      oacc = __builtin_amdgcn_mfma_f32_16x16x32_bf16(pa, vb, oacc, 0, 0, 0);
    }
#pragma unroll
    for (int r = 0; r < 4; r++)
      ao[(rowbase + q0 + lg * 4 + r) * D_MODEL + h * 64 + dn] = f2bf(oacc[r]);
  }
}

// ---------------------------------------------------------------------------
// Chunked SSM scan (|A|<0.1 => A^512 underflows; carry fixup self-terminates)
// ---------------------------------------------------------------------------
__global__ __launch_bounds__(1024) void scan_kernel(
    const unsigned short* __restrict__ qkvgu, const float* __restrict__ Avec,
    const float* __restrict__ s0, unsigned short* __restrict__ states,
    float* __restrict__ out_state)
{
  __shared__ float finals[4][256];
  const int tid = threadIdx.x;
  const int bn = tid & 255;
  const int b = bn >> 7, n = bn & 127;
  const int c = tid >> 8;
  const float a = Avec[n];
  float s = (c == 0) ? s0[bn] : 0.0f;
  const size_t ubase = (size_t)b * T_LEN * LDQ + 4096 + n;
  unsigned short* sp = states + (size_t)b * T_LEN * N_STATE + n;
  const int t0 = c * 512;
#pragma unroll 8
  for (int t = t0; t < t0 + 512; t++) {
    s = fmaf(a, s, bf2f(qkvgu[ubase + (size_t)t * LDQ]));
    sp[(size_t)t * N_STATE] = f2bf(s);
  }
  finals[c][bn] = s;
  if (c == 3) out_state[bn] = s;
  __syncthreads();
  if (c > 0) {
    const float carry = finals[c - 1][bn];
    float f = a;
    for (int t = t0; t < t0 + 512; t++) {
      if (f == 0.0f) break;
      const float v = bf2f(sp[(size_t)t * N_STATE]) + f * carry;
      sp[(size_t)t * N_STATE] = f2bf(v);
      f *= a;
    }
  }
}

// ---------------------------------------------------------------------------
// Gated fusion: out = x + g*attn + (1-g)*ssm,  g = sigmoid(xg)
// ---------------------------------------------------------------------------
__global__ __launch_bounds__(256) void fusion_kernel(
    const float* __restrict__ x, const unsigned short* __restrict__ qkvgu,
    const unsigned short* __restrict__ attn, const unsigned short* __restrict__ ssm,
    float* __restrict__ out)
{
  const int i = blockIdx.x * 256 + threadIdx.x;
  const size_t e4 = (size_t)i * 4;
  const int row = i >> 8;
  const int col = (i & 255) * 4;
  const float4 xv = *(const float4*)(x + e4);
  const ushort4 au = *(const ushort4*)(attn + e4);
  const ushort4 su = *(const ushort4*)(ssm + e4);
  const ushort4 gu = *(const ushort4*)(qkvgu + (size_t)row * LDQ + 3072 + col);
  float4 o;
  const float g0 = 1.0f / (1.0f + __expf(-bf2f(gu.x)));
  const float g1 = 1.0f / (1.0f + __expf(-bf2f(gu.y)));
  const float g2 = 1.0f / (1.0f + __expf(-bf2f(gu.z)));
  const float g3 = 1.0f / (1.0f + __expf(-bf2f(gu.w)));
  o.x = xv.x + g0 * bf2f(au.x) + (1.0f - g0) * bf2f(su.x);
  o.y = xv.y + g1 * bf2f(au.y) + (1.0f - g1) * bf2f(su.y);
  o.z = xv.z + g2 * bf2f(au.z) + (1.0f - g2) * bf2f(su.z);
  o.w = xv.w + g3 * bf2f(au.w) + (1.0f - g3) * bf2f(su.w);
  *(float4*)(out + e4) = o;
}

// ---------------------------------------------------------------------------
extern "C" void kernel_launch(void* const* d_in, const int* in_sizes, int n_in,
                              void* d_out, int out_size, void* d_ws, size_t ws_size,
                              hipStream_t stream)
{
  const float* x     = (const float*)d_in[0];
  const float* ssm0  = (const float*)d_in[1];
  const float* ln1_g = (const float*)d_in[2];
  const float* ln1_b = (const float*)d_in[3];
  const float* wq    = (const float*)d_in[4];
  const float* bq    = (const float*)d_in[5];
  const float* wk    = (const float*)d_in[6];
  const float* bk    = (const float*)d_in[7];
  const float* wv    = (const float*)d_in[8];
  const float* bv    = (const float*)d_in[9];
  const float* wo    = (const float*)d_in[10];
  const float* bo    = (const float*)d_in[11];
  const float* wg    = (const float*)d_in[12];
  const float* bg    = (const float*)d_in[13];
  const float* Av    = (const float*)d_in[14];
  const float* Bw    = (const float*)d_in[15];
  const float* Cw    = (const float*)d_in[16];
  const float* ln2_g = (const float*)d_in[17];
  const float* ln2_b = (const float*)d_in[18];
  const float* w1    = (const float*)d_in[19];
  const float* b1    = (const float*)d_in[20];
  const float* w2    = (const float*)d_in[21];
  const float* b2    = (const float*)d_in[22];

  char* p = (char*)d_ws;
  auto take = [&](size_t bytes) { char* q = p; p += (bytes + 255) & ~(size_t)255; return q; };
  unsigned short* WcatT  = (unsigned short*)take((size_t)LDQ * 1024 * 2);
  unsigned short* woT    = (unsigned short*)take((size_t)1024 * 1024 * 2);
  unsigned short* CwT    = (unsigned short*)take((size_t)1024 * 128 * 2);
  unsigned short* w1T    = (unsigned short*)take((size_t)4096 * 1024 * 2);
  unsigned short* w2T    = (unsigned short*)take((size_t)1024 * 4096 * 2);
  float*          bcat   = (float*)take((size_t)LDQ * 4);
  unsigned short* xn     = (unsigned short*)take((size_t)M_ROWS * 1024 * 2);
  unsigned short* qkvgu  = (unsigned short*)take((size_t)M_ROWS * LDQ * 2);
  unsigned short* ao     = (unsigned short*)take((size_t)M_ROWS * 1024 * 2);
  unsigned short* states = (unsigned short*)take((size_t)M_ROWS * N_STATE * 2);
  unsigned short* attn_o = (unsigned short*)take((size_t)M_ROWS * 1024 * 2);
  unsigned short* ssm_o  = (unsigned short*)take((size_t)M_ROWS * 1024 * 2);
  unsigned short* hbuf   = qkvgu;   // alias: qkvgu dead after fusion

  float* outx = (float*)d_out;
  float* out_state = outx + (size_t)M_ROWS * 1024;

  const bool big_ok =
      hipFuncSetAttribute((const void*)gemm256<0>,
                          hipFuncAttributeMaxDynamicSharedMemorySize, 131072) == hipSuccess &&
      hipFuncSetAttribute((const void*)gemm256<2>,
                          hipFuncAttributeMaxDynamicSharedMemorySize, 131072) == hipSuccess;

  // --- weight prep (bf16, transposed) ---
  transpose_cvt<<<dim3(32, 32), 256, 0, stream>>>(wq, WcatT, 1024, 1024, 0, 1024);
  transpose_cvt<<<dim3(32, 32), 256, 0, stream>>>(wk, WcatT, 1024, 1024, 1024, 1024);
  transpose_cvt<<<dim3(32, 32), 256, 0, stream>>>(wv, WcatT, 1024, 1024, 2048, 1024);
  transpose_cvt<<<dim3(32, 32), 256, 0, stream>>>(wg, WcatT, 1024, 1024, 3072, 1024);
  transpose_cvt<<<dim3(32, 4), 256, 0, stream>>>(Bw, WcatT, 1024, 128, 4096, 1024);
  transpose_cvt<<<dim3(32, 32), 256, 0, stream>>>(wo, woT, 1024, 1024, 0, 1024);
  transpose_cvt<<<dim3(4, 32), 256, 0, stream>>>(Cw, CwT, 128, 1024, 0, 128);
  transpose_cvt<<<dim3(32, 128), 256, 0, stream>>>(w1, w1T, 1024, 4096, 0, 1024);
  transpose_cvt<<<dim3(128, 32), 256, 0, stream>>>(w2, w2T, 4096, 1024, 0, 4096);
  build_bcat<<<17, 256, 0, stream>>>(bq, bk, bv, bg, bcat);

  // --- forward ---
  ln_kernel<<<M_ROWS, 256, 0, stream>>>(x, ln1_g, ln1_b, xn);
  if (big_ok)
    gemm256<0><<<256, 512, 131072, stream>>>(xn, WcatT, bcat, qkvgu, LDQ, 1024, 16);
  else
    gemm_bt<0, true, false><<<dim3(32, 64), 256, 0, stream>>>(
        xn, WcatT, bcat, nullptr, qkvgu, LDQ, 1024);
  gemm_bt<0, true, false><<<dim3(32, 4), 256, 0, stream>>>(
      xn, WcatT + (size_t)4096 * 1024, bcat + 4096, nullptr, qkvgu + 4096, LDQ, 1024);
  attn_kernel<<<dim3(128, 16, 2), 256, 0, stream>>>(qkvgu, ao);
  scan_kernel<<<1, 1024, 0, stream>>>(qkvgu, Av, ssm0, states, out_state);
  gemm_bt<0, true, false><<<dim3(32, 16), 256, 0, stream>>>(
      ao, woT, bo, nullptr, attn_o, 1024, 1024);
  gemm_bt<0, true, false><<<dim3(32, 16), 256, 0, stream>>>(
      states, CwT, nullptr, nullptr, ssm_o, 1024, 128);
  fusion_kernel<<<4096, 256, 0, stream>>>(x, qkvgu, attn_o, ssm_o, outx);
  ln_kernel<<<M_ROWS, 256, 0, stream>>>(outx, ln2_g, ln2_b, xn);
  if (big_ok)
    gemm256<2><<<256, 512, 131072, stream>>>(xn, w1T, b1, hbuf, 4096, 1024, 16);
  else
    gemm_bt<2, true, false><<<dim3(32, 64), 256, 0, stream>>>(
        xn, w1T, b1, nullptr, hbuf, 4096, 1024);
  gemm_bt<0, false, true><<<dim3(32, 16), 256, 0, stream>>>(
      hbuf, w2T, b2, outx, outx, 1024, 4096);
}

// Round 6
// 382.852 us; speedup vs baseline: 1.1707x; 1.0686x over previous
//
#include <hip/hip_runtime.h>

typedef __attribute__((ext_vector_type(8))) short bf16x8;
typedef __attribute__((ext_vector_type(4))) float f32x4;

#define D_MODEL 1024
#define T_LEN 2048
#define BATCH 2
#define N_HEADS 16
#define D_HEAD 64
#define WINDOW 256
#define N_STATE 128
#define D_FF 4096
#define N_CAT 4224   // 4*D_MODEL + N_STATE
#define LDQ 4352     // N_CAT padded to 34*128
#define M_ROWS 4096  // B*T

static __device__ __forceinline__ float bf2f(unsigned short u) {
  union { unsigned int i; float f; } v; v.i = ((unsigned int)u) << 16; return v.f;
}
static __device__ __forceinline__ unsigned short f2bf(float f) {
  unsigned int x = __float_as_uint(f);
  return (unsigned short)((x + 0x7FFFu + ((x >> 16) & 1u)) >> 16);
}

static __device__ __forceinline__ void gl_lds16(const void* g, void* l) {
  __builtin_amdgcn_global_load_lds(
      (const __attribute__((address_space(1))) unsigned int*)g,
      (__attribute__((address_space(3))) unsigned int*)l, 16, 0, 0);
}

// ---------------------------------------------------------------------------
// Transpose + f32->bf16 convert: dst[(n_off+n)*ldd + k] = bf16(src[k*N + n])
// ---------------------------------------------------------------------------
__global__ __launch_bounds__(256) void transpose_cvt(
    const float* __restrict__ src, unsigned short* __restrict__ dst,
    int K, int N, int n_off, int ldd)
{
  __shared__ float tile[32][33];
  const int kt = blockIdx.x * 32, nt = blockIdx.y * 32;
  const int c = threadIdx.x & 31, r0 = threadIdx.x >> 5;
#pragma unroll
  for (int i = 0; i < 4; i++) {
    const int r = r0 + i * 8;
    tile[r][c] = src[(size_t)(kt + r) * N + nt + c];
  }
  __syncthreads();
#pragma unroll
  for (int i = 0; i < 4; i++) {
    const int r = r0 + i * 8;
    dst[(size_t)(n_off + nt + r) * ldd + kt + c] = f2bf(tile[c][r]);
  }
}

__global__ __launch_bounds__(256) void build_bcat(
    const float* __restrict__ bq, const float* __restrict__ bk,
    const float* __restrict__ bv, const float* __restrict__ bg,
    float* __restrict__ bcat)
{
  const int i = blockIdx.x * 256 + threadIdx.x;
  if (i < LDQ) {
    float v = 0.0f;
    if (i < 1024)      v = bq[i];
    else if (i < 2048) v = bk[i - 1024];
    else if (i < 3072) v = bv[i - 2048];
    else if (i < 4096) v = bg[i - 3072];
    bcat[i] = v;
  }
}

// ---------------------------------------------------------------------------
// LayerNorm: one block per row (1024 cols), bf16 output
// ---------------------------------------------------------------------------
__global__ __launch_bounds__(256) void ln_kernel(
    const float* __restrict__ x, const float* __restrict__ g,
    const float* __restrict__ b, unsigned short* __restrict__ out)
{
  const int row = blockIdx.x, tid = threadIdx.x;
  const float4 xv = ((const float4*)(x + (size_t)row * 1024))[tid];
  float s  = xv.x + xv.y + xv.z + xv.w;
  float s2 = xv.x * xv.x + xv.y * xv.y + xv.z * xv.z + xv.w * xv.w;
#pragma unroll
  for (int off = 32; off >= 1; off >>= 1) {
    s  += __shfl_down(s, off);
    s2 += __shfl_down(s2, off);
  }
  __shared__ float red[8];
  const int wave = tid >> 6;
  if ((tid & 63) == 0) { red[wave] = s; red[4 + wave] = s2; }
  __syncthreads();
  s  = red[0] + red[1] + red[2] + red[3];
  s2 = red[4] + red[5] + red[6] + red[7];
  const float mu = s * (1.0f / 1024.0f);
  const float rs = rsqrtf(s2 * (1.0f / 1024.0f) - mu * mu + 1e-5f);
  const float4 gv = ((const float4*)g)[tid];
  const float4 bv = ((const float4*)b)[tid];
  ushort4 o;
  o.x = f2bf((xv.x - mu) * rs * gv.x + bv.x);
  o.y = f2bf((xv.y - mu) * rs * gv.y + bv.y);
  o.z = f2bf((xv.z - mu) * rs * gv.z + bv.z);
  o.w = f2bf((xv.w - mu) * rs * gv.w + bv.w);
  ((ushort4*)(out + (size_t)row * 1024))[tid] = o;
}

// ---------------------------------------------------------------------------
// m97-structure GEMM: 128x128 tile, BK=64, 4 waves of 64x64, single-buffer
// 32KB LDS (=> 3+ blocks/CU; inter-block overlap hides barrier drains),
// global_load_lds 16B staging, both-sides XOR swizzle (0 conflicts).
// C[r*ldc+c] = A[M,K] @ BT[N,K]^T + bias; ACT 0=none 2=gelu; bf16 out.
// ---------------------------------------------------------------------------
template<int ACT>
__global__ __launch_bounds__(256) void gemm128(
    const unsigned short* __restrict__ A, const unsigned short* __restrict__ BT,
    const float* __restrict__ bias, unsigned short* __restrict__ C,
    int ldc, int K)
{
  __shared__ char As[16384];   // 128 rows x 128B, swizzled
  __shared__ char Bs[16384];
  const int m0 = blockIdx.x * 128, n0 = blockIdx.y * 128;
  const int tid = threadIdx.x, lane = tid & 63, wave = tid >> 6;
  const int l15 = lane & 15, lg = lane >> 4;
  const int wm = (wave >> 1) * 64, wn = (wave & 1) * 64;
  f32x4 acc[4][4];
#pragma unroll
  for (int i = 0; i < 4; i++)
#pragma unroll
    for (int j = 0; j < 4; j++) acc[i][j] = (f32x4){0.f, 0.f, 0.f, 0.f};

  // staging sources: LDS linear dest (p = j*4096 + tid*16); global address
  // carries the inverse swizzle: row R = p>>7, col byte = (p&127)^((R&7)<<4)
  const char* srcA[4]; const char* srcB[4];
#pragma unroll
  for (int j = 0; j < 4; j++) {
    const int p = j * 4096 + tid * 16;
    const int R = p >> 7;
    const int cb = (p & 127) ^ ((R & 7) << 4);
    srcA[j] = (const char*)A  + (size_t)(m0 + R) * (size_t)(K * 2) + cb;
    srcB[j] = (const char*)BT + (size_t)(n0 + R) * (size_t)(K * 2) + cb;
  }

  const int NT = K >> 6;
  for (int t = 0; t < NT; ++t) {
    __syncthreads();
#pragma unroll
    for (int j = 0; j < 4; j++) {
      gl_lds16(srcA[j] + (size_t)t * 128, As + j * 4096 + tid * 16);
      gl_lds16(srcB[j] + (size_t)t * 128, Bs + j * 4096 + tid * 16);
    }
    __syncthreads();
    bf16x8 af[4][2], bfr[4][2];
#pragma unroll
    for (int mf = 0; mf < 4; mf++)
#pragma unroll
      for (int ks = 0; ks < 2; ks++) {
        const int R = wm + mf * 16 + l15;
        af[mf][ks] = *(const bf16x8*)(As + (R << 7) + ((ks * 64 + lg * 16) ^ ((R & 7) << 4)));
      }
#pragma unroll
    for (int nf = 0; nf < 4; nf++)
#pragma unroll
      for (int ks = 0; ks < 2; ks++) {
        const int R = wn + nf * 16 + l15;
        bfr[nf][ks] = *(const bf16x8*)(Bs + (R << 7) + ((ks * 64 + lg * 16) ^ ((R & 7) << 4)));
      }
#pragma unroll
    for (int mf = 0; mf < 4; mf++)
#pragma unroll
      for (int nf = 0; nf < 4; nf++)
#pragma unroll
        for (int ks = 0; ks < 2; ks++)
          acc[mf][nf] = __builtin_amdgcn_mfma_f32_16x16x32_bf16(
              af[mf][ks], bfr[nf][ks], acc[mf][nf], 0, 0, 0);
  }

#pragma unroll
  for (int nf = 0; nf < 4; nf++) {
    const int col = n0 + wn + nf * 16 + l15;
    const float bv = bias[col];
#pragma unroll
    for (int mf = 0; mf < 4; mf++) {
      const int rbase = m0 + wm + mf * 16 + lg * 4;
#pragma unroll
      for (int r = 0; r < 4; r++) {
        float v = acc[mf][nf][r] + bv;
        if (ACT == 2) v = 0.5f * v * (1.0f + erff(v * 0.70710678118654752f));
        C[(size_t)(rbase + r) * ldc + col] = f2bf(v);
      }
    }
  }
}

// ---------------------------------------------------------------------------
// Small GEMM: 128x64 tile, BK=64, single-buffer LDS, m97 2-barrier loop,
// XOR-swizzled LDS (conflict-free).
// ---------------------------------------------------------------------------
template<int ACT, bool OUT_BF16, bool RESID>
__global__ __launch_bounds__(256, 3) void gemm_bt(
    const unsigned short* __restrict__ A, const unsigned short* __restrict__ BT,
    const float* __restrict__ bias, const float* __restrict__ resid,
    void* __restrict__ Cout, int ldc, int K)
{
  __shared__ char As[16384];
  __shared__ char Bs[8192];
  const int m0 = blockIdx.x * 128, n0 = blockIdx.y * 64;
  const int tid = threadIdx.x, lane = tid & 63, wave = tid >> 6;
  const int l15 = lane & 15, lg = lane >> 4;
  const int wm = (wave & 1) * 64, wn = (wave >> 1) * 32;
  f32x4 acc[4][2];
#pragma unroll
  for (int i = 0; i < 4; i++)
#pragma unroll
    for (int j = 0; j < 2; j++) acc[i][j] = (f32x4){0.f, 0.f, 0.f, 0.f};

  const char* srcA[4]; const char* srcB[2];
#pragma unroll
  for (int j = 0; j < 4; j++) {
    const int p = j * 4096 + tid * 16;
    const int R = p >> 7;
    const int cb = (p & 127) ^ ((R & 7) << 4);
    srcA[j] = (const char*)A + (size_t)(m0 + R) * (size_t)(K * 2) + cb;
    if (j < 2) srcB[j] = (const char*)BT + (size_t)(n0 + R) * (size_t)(K * 2) + cb;
  }

  const int NT = K >> 6;
  for (int t = 0; t < NT; ++t) {
    __syncthreads();
#pragma unroll
    for (int j = 0; j < 4; j++)
      gl_lds16(srcA[j] + (size_t)t * 128, As + j * 4096 + tid * 16);
#pragma unroll
    for (int j = 0; j < 2; j++)
      gl_lds16(srcB[j] + (size_t)t * 128, Bs + j * 4096 + tid * 16);
    __syncthreads();
    bf16x8 af[4][2], bfr[2][2];
#pragma unroll
    for (int mf = 0; mf < 4; mf++)
#pragma unroll
      for (int ks = 0; ks < 2; ks++) {
        const int R = wm + mf * 16 + l15;
        af[mf][ks] = *(const bf16x8*)(As + (R << 7) + ((ks * 64 + lg * 16) ^ ((R & 7) << 4)));
      }
#pragma unroll
    for (int nf = 0; nf < 2; nf++)
#pragma unroll
      for (int ks = 0; ks < 2; ks++) {
        const int R = wn + nf * 16 + l15;
        bfr[nf][ks] = *(const bf16x8*)(Bs + (R << 7) + ((ks * 64 + lg * 16) ^ ((R & 7) << 4)));
      }
#pragma unroll
    for (int mf = 0; mf < 4; mf++)
#pragma unroll
      for (int nf = 0; nf < 2; nf++)
#pragma unroll
        for (int ks = 0; ks < 2; ks++)
          acc[mf][nf] = __builtin_amdgcn_mfma_f32_16x16x32_bf16(
              af[mf][ks], bfr[nf][ks], acc[mf][nf], 0, 0, 0);
  }

#pragma unroll
  for (int nf = 0; nf < 2; nf++) {
    const int col = n0 + wn + nf * 16 + l15;
    const float bv = bias ? bias[col] : 0.0f;
#pragma unroll
    for (int mf = 0; mf < 4; mf++) {
      const int rbase = m0 + wm + mf * 16 + lg * 4;
#pragma unroll
      for (int r = 0; r < 4; r++) {
        float v = acc[mf][nf][r] + bv;
        if (ACT == 2) v = 0.5f * v * (1.0f + erff(v * 0.70710678118654752f));
        const size_t idx = (size_t)(rbase + r) * ldc + col;
        if (RESID) v += resid[idx];
        if (OUT_BF16) ((unsigned short*)Cout)[idx] = f2bf(v);
        else          ((float*)Cout)[idx] = v;
      }
    }
  }
}

// ---------------------------------------------------------------------------
// Windowed causal attention, all-MFMA (r2-verified, LDQ stride)
// ---------------------------------------------------------------------------
__global__ __launch_bounds__(256) void attn_kernel(
    const unsigned short* __restrict__ qkvgu, unsigned short* __restrict__ ao)
{
  __shared__ float S[16][276];
  __shared__ unsigned short Vt[288][68];
  unsigned short* P = (unsigned short*)&S[0][0];

  const int bx = ((blockIdx.x & 7) << 4) | (blockIdx.x >> 3);
  const int q0 = bx * 16;
  const int h  = blockIdx.y;
  const int b  = blockIdx.z;
  const int tid = threadIdx.x, lane = tid & 63, wave = tid >> 6;
  const int l15 = lane & 15, lg = lane >> 4;
  const size_t rowbase = (size_t)b * T_LEN;

  {
    const int cg = (tid & 3) * 16;
    const int rr = tid >> 2;
#pragma unroll
    for (int j = 0; j < 5; j++) {
      const int row = j * 64 + rr;
      if (row < 288) {
        const int vrow = q0 - 256 + row;
        uint4 d0 = {0u, 0u, 0u, 0u}, d1 = {0u, 0u, 0u, 0u};
        if (vrow >= 0 && row < 272) {
          const unsigned short* vp = qkvgu + (rowbase + vrow) * LDQ + 2048 + h * 64 + cg;
          d0 = *(const uint4*)vp;
          d1 = *(const uint4*)(vp + 8);
        }
        unsigned short* wp = &Vt[row][cg];
        ((uint2*)wp)[0] = make_uint2(d0.x, d0.y);
        ((uint2*)wp)[1] = make_uint2(d0.z, d0.w);
        ((uint2*)wp)[2] = make_uint2(d1.x, d1.y);
        ((uint2*)wp)[3] = make_uint2(d1.z, d1.w);
      }
    }
  }

  {
    const unsigned short* qp = qkvgu + (rowbase + q0 + l15) * LDQ + h * 64 + lg * 8;
    const bf16x8 aq0 = *(const bf16x8*)qp;
    const bf16x8 aq1 = *(const bf16x8*)(qp + 32);
    for (int kt = wave; kt < 17; kt += 4) {
      const int kbase = q0 - 256 + kt * 16;
      const int krow = kbase + l15;
      const int krc = krow < 0 ? 0 : krow;
      const unsigned short* kp = qkvgu + (rowbase + krc) * LDQ + 1024 + h * 64 + lg * 8;
      const bf16x8 bk0 = *(const bf16x8*)kp;
      const bf16x8 bk1 = *(const bf16x8*)(kp + 32);
      f32x4 sacc = (f32x4){0.f, 0.f, 0.f, 0.f};
      sacc = __builtin_amdgcn_mfma_f32_16x16x32_bf16(aq0, bk0, sacc, 0, 0, 0);
      sacc = __builtin_amdgcn_mfma_f32_16x16x32_bf16(aq1, bk1, sacc, 0, 0, 0);
#pragma unroll
      for (int r = 0; r < 4; r++) {
        const int qi = q0 + lg * 4 + r;
        const int kj = kbase + l15;
        const bool ok = (kj >= 0) && (kj <= qi) && (qi - kj < WINDOW);
        S[lg * 4 + r][kt * 16 + l15] = ok ? sacc[r] * 0.125f : -1e30f;
      }
    }
  }
  __syncthreads();

  {
    const int q = tid >> 4, sub = tid & 15;
    float mx = -1e30f;
    for (int c = sub; c < 272; c += 16) mx = fmaxf(mx, S[q][c]);
#pragma unroll
    for (int off = 8; off >= 1; off >>= 1) mx = fmaxf(mx, __shfl_xor(mx, off));
    float sum = 0.f;
    for (int c = sub; c < 272; c += 16) sum += __expf(S[q][c] - mx);
#pragma unroll
    for (int off = 8; off >= 1; off >>= 1) sum += __shfl_xor(sum, off);
    const float inv = 1.0f / sum;
    unsigned short* Prow = P + q * 552;
    for (int c = sub; c < 288; c += 16) {
      const float pv = (c < 272) ? __expf(S[q][c] - mx) * inv : 0.0f;
      Prow[c] = f2bf(pv);
    }
  }
  __syncthreads();

  {
    f32x4 oacc = (f32x4){0.f, 0.f, 0.f, 0.f};
    const int dn = wave * 16 + l15;
#pragma unroll
    for (int ks = 0; ks < 9; ks++) {
      const bf16x8 pa = *(const bf16x8*)(P + l15 * 552 + ks * 32 + lg * 8);
      bf16x8 vb;
      const int kb = ks * 32 + lg * 8;
#pragma unroll
      for (int j = 0; j < 8; j++) ((unsigned short*)&vb)[j] = Vt[kb + j][dn];
      oacc = __builtin_amdgcn_mfma_f32_16x16x32_bf16(pa, vb, oacc, 0, 0, 0);
    }
#pragma unroll
    for (int r = 0; r < 4; r++)
      ao[(rowbase + q0 + lg * 4 + r) * D_MODEL + h * 64 + dn] = f2bf(oacc[r]);
  }
}

// ---------------------------------------------------------------------------
// Chunked SSM scan (|A|<0.1 => A^512 underflows; carry fixup self-terminates)
// ---------------------------------------------------------------------------
__global__ __launch_bounds__(1024) void scan_kernel(
    const unsigned short* __restrict__ qkvgu, const float* __restrict__ Avec,
    const float* __restrict__ s0, unsigned short* __restrict__ states,
    float* __restrict__ out_state)
{
  __shared__ float finals[4][256];
  const int tid = threadIdx.x;
  const int bn = tid & 255;
  const int b = bn >> 7, n = bn & 127;
  const int c = tid >> 8;
  const float a = Avec[n];
  float s = (c == 0) ? s0[bn] : 0.0f;
  const size_t ubase = (size_t)b * T_LEN * LDQ + 4096 + n;
  unsigned short* sp = states + (size_t)b * T_LEN * N_STATE + n;
  const int t0 = c * 512;
#pragma unroll 8
  for (int t = t0; t < t0 + 512; t++) {
    s = fmaf(a, s, bf2f(qkvgu[ubase + (size_t)t * LDQ]));
    sp[(size_t)t * N_STATE] = f2bf(s);
  }
  finals[c][bn] = s;
  if (c == 3) out_state[bn] = s;
  __syncthreads();
  if (c > 0) {
    const float carry = finals[c - 1][bn];
    float f = a;
    for (int t = t0; t < t0 + 512; t++) {
      if (f == 0.0f) break;
      const float v = bf2f(sp[(size_t)t * N_STATE]) + f * carry;
      sp[(size_t)t * N_STATE] = f2bf(v);
      f *= a;
    }
  }
}

// ---------------------------------------------------------------------------
// Gated fusion: out = x + g*attn + (1-g)*ssm,  g = sigmoid(xg)
// ---------------------------------------------------------------------------
__global__ __launch_bounds__(256) void fusion_kernel(
    const float* __restrict__ x, const unsigned short* __restrict__ qkvgu,
    const unsigned short* __restrict__ attn, const unsigned short* __restrict__ ssm,
    float* __restrict__ out)
{
  const int i = blockIdx.x * 256 + threadIdx.x;
  const size_t e4 = (size_t)i * 4;
  const int row = i >> 8;
  const int col = (i & 255) * 4;
  const float4 xv = *(const float4*)(x + e4);
  const ushort4 au = *(const ushort4*)(attn + e4);
  const ushort4 su = *(const ushort4*)(ssm + e4);
  const ushort4 gu = *(const ushort4*)(qkvgu + (size_t)row * LDQ + 3072 + col);
  float4 o;
  const float g0 = 1.0f / (1.0f + __expf(-bf2f(gu.x)));
  const float g1 = 1.0f / (1.0f + __expf(-bf2f(gu.y)));
  const float g2 = 1.0f / (1.0f + __expf(-bf2f(gu.z)));
  const float g3 = 1.0f / (1.0f + __expf(-bf2f(gu.w)));
  o.x = xv.x + g0 * bf2f(au.x) + (1.0f - g0) * bf2f(su.x);
  o.y = xv.y + g1 * bf2f(au.y) + (1.0f - g1) * bf2f(su.y);
  o.z = xv.z + g2 * bf2f(au.z) + (1.0f - g2) * bf2f(su.z);
  o.w = xv.w + g3 * bf2f(au.w) + (1.0f - g3) * bf2f(su.w);
  *(float4*)(out + e4) = o;
}

// ---------------------------------------------------------------------------
extern "C" void kernel_launch(void* const* d_in, const int* in_sizes, int n_in,
                              void* d_out, int out_size, void* d_ws, size_t ws_size,
                              hipStream_t stream)
{
  const float* x     = (const float*)d_in[0];
  const float* ssm0  = (const float*)d_in[1];
  const float* ln1_g = (const float*)d_in[2];
  const float* ln1_b = (const float*)d_in[3];
  const float* wq    = (const float*)d_in[4];
  const float* bq    = (const float*)d_in[5];
  const float* wk    = (const float*)d_in[6];
  const float* bk    = (const float*)d_in[7];
  const float* wv    = (const float*)d_in[8];
  const float* bv    = (const float*)d_in[9];
  const float* wo    = (const float*)d_in[10];
  const float* bo    = (const float*)d_in[11];
  const float* wg    = (const float*)d_in[12];
  const float* bg    = (const float*)d_in[13];
  const float* Av    = (const float*)d_in[14];
  const float* Bw    = (const float*)d_in[15];
  const float* Cw    = (const float*)d_in[16];
  const float* ln2_g = (const float*)d_in[17];
  const float* ln2_b = (const float*)d_in[18];
  const float* w1    = (const float*)d_in[19];
  const float* b1    = (const float*)d_in[20];
  const float* w2    = (const float*)d_in[21];
  const float* b2    = (const float*)d_in[22];

  char* p = (char*)d_ws;
  auto take = [&](size_t bytes) { char* q = p; p += (bytes + 255) & ~(size_t)255; return q; };
  unsigned short* WcatT  = (unsigned short*)take((size_t)LDQ * 1024 * 2);
  unsigned short* woT    = (unsigned short*)take((size_t)1024 * 1024 * 2);
  unsigned short* CwT    = (unsigned short*)take((size_t)1024 * 128 * 2);
  unsigned short* w1T    = (unsigned short*)take((size_t)4096 * 1024 * 2);
  unsigned short* w2T    = (unsigned short*)take((size_t)1024 * 4096 * 2);
  float*          bcat   = (float*)take((size_t)LDQ * 4);
  unsigned short* xn     = (unsigned short*)take((size_t)M_ROWS * 1024 * 2);
  unsigned short* qkvgu  = (unsigned short*)take((size_t)M_ROWS * LDQ * 2);
  unsigned short* ao     = (unsigned short*)take((size_t)M_ROWS * 1024 * 2);
  unsigned short* states = (unsigned short*)take((size_t)M_ROWS * N_STATE * 2);
  unsigned short* attn_o = (unsigned short*)take((size_t)M_ROWS * 1024 * 2);
  unsigned short* ssm_o  = (unsigned short*)take((size_t)M_ROWS * 1024 * 2);
  unsigned short* hbuf   = qkvgu;   // alias: qkvgu dead after fusion

  float* outx = (float*)d_out;
  float* out_state = outx + (size_t)M_ROWS * 1024;

  // --- weight prep (bf16, transposed) ---
  transpose_cvt<<<dim3(32, 32), 256, 0, stream>>>(wq, WcatT, 1024, 1024, 0, 1024);
  transpose_cvt<<<dim3(32, 32), 256, 0, stream>>>(wk, WcatT, 1024, 1024, 1024, 1024);
  transpose_cvt<<<dim3(32, 32), 256, 0, stream>>>(wv, WcatT, 1024, 1024, 2048, 1024);
  transpose_cvt<<<dim3(32, 32), 256, 0, stream>>>(wg, WcatT, 1024, 1024, 3072, 1024);
  transpose_cvt<<<dim3(32, 4), 256, 0, stream>>>(Bw, WcatT, 1024, 128, 4096, 1024);
  transpose_cvt<<<dim3(32, 32), 256, 0, stream>>>(wo, woT, 1024, 1024, 0, 1024);
  transpose_cvt<<<dim3(4, 32), 256, 0, stream>>>(Cw, CwT, 128, 1024, 0, 128);
  transpose_cvt<<<dim3(32, 128), 256, 0, stream>>>(w1, w1T, 1024, 4096, 0, 1024);
  transpose_cvt<<<dim3(128, 32), 256, 0, stream>>>(w2, w2T, 4096, 1024, 0, 4096);
  build_bcat<<<17, 256, 0, stream>>>(bq, bk, bv, bg, bcat);

  // --- forward ---
  ln_kernel<<<M_ROWS, 256, 0, stream>>>(x, ln1_g, ln1_b, xn);
  gemm128<0><<<dim3(32, 34), 256, 0, stream>>>(xn, WcatT, bcat, qkvgu, LDQ, 1024);
  attn_kernel<<<dim3(128, 16, 2), 256, 0, stream>>>(qkvgu, ao);
  scan_kernel<<<1, 1024, 0, stream>>>(qkvgu, Av, ssm0, states, out_state);
  gemm_bt<0, true, false><<<dim3(32, 16), 256, 0, stream>>>(
      ao, woT, bo, nullptr, attn_o, 1024, 1024);
  gemm_bt<0, true, false><<<dim3(32, 16), 256, 0, stream>>>(
      states, CwT, nullptr, nullptr, ssm_o, 1024, 128);
  fusion_kernel<<<4096, 256, 0, stream>>>(x, qkvgu, attn_o, ssm_o, outx);
  ln_kernel<<<M_ROWS, 256, 0, stream>>>(outx, ln2_g, ln2_b, xn);
  gemm128<2><<<dim3(32, 32), 256, 0, stream>>>(xn, w1T, b1, hbuf, 4096, 1024);
  gemm_bt<0, false, true><<<dim3(32, 16), 256, 0, stream>>>(
      hbuf, w2T, b2, outx, outx, 1024, 4096);
}